// Round 1
// baseline (8721.352 us; speedup 1.0000x reference)
//
#include <hip/hip_runtime.h>

static inline int idiv_up(long a, long b) { return (int)((a + b - 1) / b); }

// ---------------- degree ----------------
__global__ __launch_bounds__(256) void k_deg(const int* __restrict__ dst,
                                             float* __restrict__ deg, int E) {
    int e = blockIdx.x * 256 + threadIdx.x;
    if (e < E) unsafeAtomicAdd(&deg[dst[e]], 1.0f);
}

__global__ __launch_bounds__(256) void k_invdeg(float* deg, int n) {
    int i = blockIdx.x * 256 + threadIdx.x;
    if (i < n) deg[i] = 1.0f / fmaxf(deg[i], 1.0f);
}

// ---------------- scatter-add (sum aggregation), d=128 ----------------
// 32 lanes per edge; each lane moves one float4 (4 consecutive feats).
__global__ __launch_bounds__(256) void k_scatter(const float* __restrict__ x,
                                                 const int* __restrict__ src,
                                                 const int* __restrict__ dst,
                                                 float* agg, int E) {
    int t = blockIdx.x * 256 + threadIdx.x;
    int e = t >> 5;
    if (e >= E) return;
    int l = t & 31;
    int s = src[e], d = dst[e];
    float4 v = ((const float4*)(x + (size_t)s * 128))[l];
    float* a = agg + (size_t)d * 128 + (l << 2);
    unsafeAtomicAdd(a + 0, v.x);
    unsafeAtomicAdd(a + 1, v.y);
    unsafeAtomicAdd(a + 2, v.z);
    unsafeAtomicAdd(a + 3, v.w);
}

// ---------------- fused SAGE linear: out = (agg*invdeg)@Wl + bl + xr@Wr ----------------
// d_in = 128, d_out = 128. 16 rows per 256-thread block; thread = 2 rows x 4 cols.
// NOTE: `agg` and `out` may alias (in-place): each block reads only its own
// rows into LDS before writing them, so no __restrict__ on those two.
__global__ __launch_bounds__(256) void k_mm128(const float* agg,
                                               const float* __restrict__ invdeg,
                                               const float* __restrict__ xr,
                                               const float* __restrict__ Wl,
                                               const float* __restrict__ bl,
                                               const float* __restrict__ Wr,
                                               float* out, int n, int doRelu) {
    __shared__ float s_agg[16][128];
    __shared__ float s_x[16][128];
    const int row0 = blockIdx.x * 16;

    for (int idx = threadIdx.x; idx < 16 * 128; idx += 256) {
        const int r = idx >> 7, k = idx & 127;
        const int row = row0 + r;
        float a = 0.f, xv = 0.f;
        if (row < n) {
            a = agg[(size_t)row * 128 + k] * invdeg[row];
            xv = xr[(size_t)row * 128 + k];
        }
        s_agg[r][k] = a;
        s_x[r][k] = xv;
    }
    __syncthreads();

    const int lane32 = threadIdx.x & 31;
    const int c4 = lane32 << 2;           // col base: 0,4,...,124
    const int r0 = threadIdx.x >> 5;      // 0..7  -> rows r0 and r0+8
    const float4* Wl4 = (const float4*)Wl;
    const float4* Wr4 = (const float4*)Wr;

    float4 acc0 = {0.f, 0.f, 0.f, 0.f};
    float4 acc1 = {0.f, 0.f, 0.f, 0.f};

#pragma unroll 4
    for (int k = 0; k < 128; ++k) {
        const float4 wl = Wl4[k * 32 + lane32];
        const float4 wr = Wr4[k * 32 + lane32];
        const float a0 = s_agg[r0][k];
        const float a1 = s_agg[r0 + 8][k];
        const float x0 = s_x[r0][k];
        const float x1 = s_x[r0 + 8][k];
        acc0.x = fmaf(a0, wl.x, acc0.x); acc0.x = fmaf(x0, wr.x, acc0.x);
        acc0.y = fmaf(a0, wl.y, acc0.y); acc0.y = fmaf(x0, wr.y, acc0.y);
        acc0.z = fmaf(a0, wl.z, acc0.z); acc0.z = fmaf(x0, wr.z, acc0.z);
        acc0.w = fmaf(a0, wl.w, acc0.w); acc0.w = fmaf(x0, wr.w, acc0.w);
        acc1.x = fmaf(a1, wl.x, acc1.x); acc1.x = fmaf(x1, wr.x, acc1.x);
        acc1.y = fmaf(a1, wl.y, acc1.y); acc1.y = fmaf(x1, wr.y, acc1.y);
        acc1.z = fmaf(a1, wl.z, acc1.z); acc1.z = fmaf(x1, wr.z, acc1.z);
        acc1.w = fmaf(a1, wl.w, acc1.w); acc1.w = fmaf(x1, wr.w, acc1.w);
    }

    const float4 bb = ((const float4*)bl)[lane32];
    float4 o0, o1;
    o0.x = acc0.x + bb.x; o0.y = acc0.y + bb.y; o0.z = acc0.z + bb.z; o0.w = acc0.w + bb.w;
    o1.x = acc1.x + bb.x; o1.y = acc1.y + bb.y; o1.z = acc1.z + bb.z; o1.w = acc1.w + bb.w;
    if (doRelu) {
        o0.x = fmaxf(o0.x, 0.f); o0.y = fmaxf(o0.y, 0.f); o0.z = fmaxf(o0.z, 0.f); o0.w = fmaxf(o0.w, 0.f);
        o1.x = fmaxf(o1.x, 0.f); o1.y = fmaxf(o1.y, 0.f); o1.z = fmaxf(o1.z, 0.f); o1.w = fmaxf(o1.w, 0.f);
    }
    const int ra = row0 + r0;
    const int rb = ra + 8;
    if (ra < n) *(float4*)(out + (size_t)ra * 128 + c4) = o0;
    if (rb < n) *(float4*)(out + (size_t)rb * 128 + c4) = o1;
}

// ---------------- layer 3: d_out = 40, no relu ----------------
// 8 rows per 320-thread block: thread = (row = tid/40, col = tid%40).
__global__ __launch_bounds__(320) void k_mm40(const float* __restrict__ agg,
                                              const float* __restrict__ invdeg,
                                              const float* __restrict__ xr,
                                              const float* __restrict__ Wl,
                                              const float* __restrict__ bl,
                                              const float* __restrict__ Wr,
                                              float* __restrict__ out, int n) {
    __shared__ float s_agg[8][128];
    __shared__ float s_x[8][128];
    const int row0 = blockIdx.x * 8;

    for (int idx = threadIdx.x; idx < 8 * 128; idx += 320) {
        const int r = idx >> 7, k = idx & 127;
        const int row = row0 + r;
        float a = 0.f, xv = 0.f;
        if (row < n) {
            a = agg[(size_t)row * 128 + k] * invdeg[row];
            xv = xr[(size_t)row * 128 + k];
        }
        s_agg[r][k] = a;
        s_x[r][k] = xv;
    }
    __syncthreads();

    const int col = threadIdx.x % 40;
    const int r = threadIdx.x / 40;
    float acc = 0.f;
#pragma unroll 4
    for (int k = 0; k < 128; ++k) {
        acc = fmaf(s_agg[r][k], Wl[k * 40 + col], acc);
        acc = fmaf(s_x[r][k], Wr[k * 40 + col], acc);
    }
    const int row = row0 + r;
    if (row < n) out[(size_t)row * 40 + col] = acc + bl[col];
}

extern "C" void kernel_launch(void* const* d_in, const int* in_sizes, int n_in,
                              void* d_out, int out_size, void* d_ws, size_t ws_size,
                              hipStream_t stream) {
    const float* x   = (const float*)d_in[0];
    const int*   ei  = (const int*)d_in[1];
    const float* Wl1 = (const float*)d_in[2];
    const float* bl1 = (const float*)d_in[3];
    const float* Wr1 = (const float*)d_in[4];
    const float* Wl2 = (const float*)d_in[5];
    const float* bl2 = (const float*)d_in[6];
    const float* Wr2 = (const float*)d_in[7];
    const float* Wl3 = (const float*)d_in[8];
    const float* bl3 = (const float*)d_in[9];
    const float* Wr3 = (const float*)d_in[10];
    float* out = (float*)d_out;

    const int N = in_sizes[0] / 128;
    const int E = in_sizes[1] / 2;
    const int* src = ei;
    const int* dst = ei + E;

    const size_t NB = (size_t)N * 128 * sizeof(float);  // 51.2 MB
    char* ws = (char*)d_ws;
    float* deg  = (float*)ws;                               // N floats
    float* bufA = (float*)(ws + (((size_t)N * 4 + 1023) & ~(size_t)1023));
    float* bufB = (float*)((char*)bufA + NB);

    const int degBlocks  = idiv_up(E, 256);
    const int nBlocks    = idiv_up(N, 256);
    const int scatBlocks = idiv_up((long)E * 32, 256);
    const int mmBlocks   = idiv_up(N, 16);
    const int mm40Blocks = idiv_up(N, 8);

    // degree (shared by all 3 layers)
    hipMemsetAsync(deg, 0, (size_t)N * sizeof(float), stream);
    k_deg<<<degBlocks, 256, 0, stream>>>(dst, deg, E);
    k_invdeg<<<nBlocks, 256, 0, stream>>>(deg, N);

    // layer 1: agg(x) -> bufA ; h1 = relu(...) -> bufB
    hipMemsetAsync(bufA, 0, NB, stream);
    k_scatter<<<scatBlocks, 256, 0, stream>>>(x, src, dst, bufA, E);
    k_mm128<<<mmBlocks, 256, 0, stream>>>(bufA, deg, x, Wl1, bl1, Wr1, bufB, N, 1);

    // layer 2: agg(h1) -> bufA ; h2 = relu(...) -> bufA (in-place over agg)
    hipMemsetAsync(bufA, 0, NB, stream);
    k_scatter<<<scatBlocks, 256, 0, stream>>>(bufB, src, dst, bufA, E);
    k_mm128<<<mmBlocks, 256, 0, stream>>>(bufA, deg, bufB, Wl2, bl2, Wr2, bufA, N, 1);

    // layer 3: agg(h2) -> bufB ; out = agg@Wl3 + bl3 + h2@Wr3
    hipMemsetAsync(bufB, 0, NB, stream);
    k_scatter<<<scatBlocks, 256, 0, stream>>>(bufA, src, dst, bufB, E);
    k_mm40<<<mm40Blocks, 320, 0, stream>>>(bufB, deg, bufA, Wl3, bl3, Wr3, out, N);
}

// Round 2
// 843.871 us; speedup vs baseline: 10.3349x; 10.3349x over previous
//
#include <hip/hip_runtime.h>

static inline int idiv_up(long a, long b) { return (int)((a + b - 1) / b); }

// ================= CSR construction =================

__global__ __launch_bounds__(256) void k_count(const int* __restrict__ dst,
                                               int* __restrict__ degi, int E) {
    int e = blockIdx.x * 256 + threadIdx.x;
    if (e < E) atomicAdd(&degi[dst[e]], 1);
}

// invdeg written in place over degi (float pun)
__global__ __launch_bounds__(256) void k_invdeg(int* degi, int n) {
    int i = blockIdx.x * 256 + threadIdx.x;
    if (i < n) {
        int d = degi[i];
        ((float*)degi)[i] = 1.0f / fmaxf((float)d, 1.0f);
    }
}

// block-level exclusive scan: 1024 elems/block (256 thr x 4), writes local
// exclusive prefixes to rowptr and block totals to partials.
__global__ __launch_bounds__(256) void k_scan1(const int* __restrict__ degi,
                                               int* __restrict__ rowptr,
                                               int* __restrict__ partials, int n) {
    __shared__ int wt[4];
    const int base = blockIdx.x * 1024 + threadIdx.x * 4;
    int v[4];
    int sum = 0;
#pragma unroll
    for (int j = 0; j < 4; ++j) {
        int g = base + j;
        v[j] = (g < n) ? degi[g] : 0;
        sum += v[j];
    }
    const int lane = threadIdx.x & 63;
    const int wid = threadIdx.x >> 6;
    int incl = sum;
    for (int off = 1; off < 64; off <<= 1) {
        int t = __shfl_up(incl, off, 64);
        if (lane >= off) incl += t;
    }
    if (lane == 63) wt[wid] = incl;
    __syncthreads();
    int woff = 0;
    for (int w = 0; w < wid; ++w) woff += wt[w];
    int run = woff + incl - sum;   // exclusive prefix of this thread's 4 elems
#pragma unroll
    for (int j = 0; j < 4; ++j) {
        int g = base + j;
        if (g < n) rowptr[g] = run;
        run += v[j];
    }
    if (threadIdx.x == 255) partials[blockIdx.x] = woff + incl;
}

// single-block exclusive scan of partials (handles arbitrary nb via carry loop)
__global__ __launch_bounds__(256) void k_scan2(int* p, int nb) {
    __shared__ int wt[4];
    __shared__ int carry;
    if (threadIdx.x == 0) carry = 0;
    __syncthreads();
    for (int bs = 0; bs < nb; bs += 256) {
        const int i = bs + threadIdx.x;
        int v = (i < nb) ? p[i] : 0;
        const int lane = threadIdx.x & 63;
        const int wid = threadIdx.x >> 6;
        int incl = v;
        for (int off = 1; off < 64; off <<= 1) {
            int t = __shfl_up(incl, off, 64);
            if (lane >= off) incl += t;
        }
        if (lane == 63) wt[wid] = incl;
        __syncthreads();
        int woff = 0;
        for (int w = 0; w < wid; ++w) woff += wt[w];
        int excl = carry + woff + incl - v;
        if (i < nb) p[i] = excl;
        __syncthreads();
        if (threadIdx.x == 255) carry += woff + incl;
        __syncthreads();
    }
}

__global__ __launch_bounds__(256) void k_scan3(int* __restrict__ rowptr,
                                               const int* __restrict__ partials,
                                               int n, int E) {
    const int base = blockIdx.x * 1024;
    const int add = partials[blockIdx.x];
    for (int i = threadIdx.x; i < 1024; i += 256) {
        int g = base + i;
        if (g < n) rowptr[g] += add;
    }
    if (blockIdx.x == 0 && threadIdx.x == 0) rowptr[n] = E;
}

__global__ __launch_bounds__(256) void k_fill(const int* __restrict__ src,
                                              const int* __restrict__ dst,
                                              const int* __restrict__ rowptr,
                                              int* __restrict__ cursor,
                                              int* __restrict__ col, int E) {
    int e = blockIdx.x * 256 + threadIdx.x;
    if (e >= E) return;
    int d = dst[e];
    int pos = rowptr[d] + atomicAdd(&cursor[d], 1);
    col[pos] = src[e];
}

// ================= mean aggregation (gather, no atomics) =================
// 32 lanes per node; lane l owns feats [4l, 4l+4). Neighbor ids batched via shfl.
__global__ __launch_bounds__(256) void k_agg(const float* __restrict__ x,
                                             const int* __restrict__ rowptr,
                                             const int* __restrict__ col,
                                             const float* __restrict__ invdeg,
                                             float* __restrict__ agg, int n) {
    const int t = blockIdx.x * 256 + threadIdx.x;
    const int node = t >> 5;
    if (node >= n) return;
    const int l = t & 31;
    const int s0 = rowptr[node], s1 = rowptr[node + 1];
    float4 acc = {0.f, 0.f, 0.f, 0.f};
    for (int base = s0; base < s1; base += 32) {
        int c = (base + l < s1) ? col[base + l] : 0;
        const int cnt = min(32, s1 - base);
        for (int j = 0; j < cnt; ++j) {
            int srcn = __shfl(c, j, 32);
            float4 v = ((const float4*)(x + (size_t)srcn * 128))[l];
            acc.x += v.x; acc.y += v.y; acc.z += v.z; acc.w += v.w;
        }
    }
    const float inv = invdeg[node];
    acc.x *= inv; acc.y *= inv; acc.z *= inv; acc.w *= inv;
    ((float4*)(agg + (size_t)node * 128))[l] = acc;
}

// ================= fused SAGE linear (d_out=128) =================
// out = agg@Wl + bl + xr@Wr  (agg pre-scaled by invdeg)
// 64 rows/block, 256 threads, thread = 8 rows x 4 cols. LDS 64KB.
// `agg`/`out` may alias (in-place): block reads only its own rows before writing.
__global__ __launch_bounds__(256) void k_mm128(const float* agg,
                                               const float* xr_a,
                                               const float* __restrict__ Wl,
                                               const float* __restrict__ bl,
                                               const float* __restrict__ Wr,
                                               float* out, int n, int doRelu) {
    __shared__ float s_agg[64][128];
    __shared__ float s_x[64][128];
    const int row0 = blockIdx.x * 64;

    for (int idx = threadIdx.x; idx < 64 * 32; idx += 256) {
        const int r = idx >> 5, k4 = idx & 31;
        const int row = row0 + r;
        float4 a = {0.f, 0.f, 0.f, 0.f}, xv = {0.f, 0.f, 0.f, 0.f};
        if (row < n) {
            a  = ((const float4*)(agg  + (size_t)row * 128))[k4];
            xv = ((const float4*)(xr_a + (size_t)row * 128))[k4];
        }
        ((float4*)s_agg[r])[k4] = a;
        ((float4*)s_x[r])[k4] = xv;
    }
    __syncthreads();

    const int lane32 = threadIdx.x & 31;
    const int rg = threadIdx.x >> 5;          // 0..7 -> rows rg*8 .. rg*8+7
    const float4* Wl4 = (const float4*)Wl;
    const float4* Wr4 = (const float4*)Wr;

    float4 acc[8];
#pragma unroll
    for (int j = 0; j < 8; ++j) acc[j] = make_float4(0.f, 0.f, 0.f, 0.f);

#pragma unroll 4
    for (int k = 0; k < 128; ++k) {
        const float4 wl = Wl4[k * 32 + lane32];
        const float4 wr = Wr4[k * 32 + lane32];
#pragma unroll
        for (int j = 0; j < 8; ++j) {
            const float a = s_agg[rg * 8 + j][k];
            const float xv = s_x[rg * 8 + j][k];
            acc[j].x = fmaf(a, wl.x, fmaf(xv, wr.x, acc[j].x));
            acc[j].y = fmaf(a, wl.y, fmaf(xv, wr.y, acc[j].y));
            acc[j].z = fmaf(a, wl.z, fmaf(xv, wr.z, acc[j].z));
            acc[j].w = fmaf(a, wl.w, fmaf(xv, wr.w, acc[j].w));
        }
    }

    const float4 bb = ((const float4*)bl)[lane32];
#pragma unroll
    for (int j = 0; j < 8; ++j) {
        const int row = row0 + rg * 8 + j;
        if (row >= n) break;
        float4 o;
        o.x = acc[j].x + bb.x; o.y = acc[j].y + bb.y;
        o.z = acc[j].z + bb.z; o.w = acc[j].w + bb.w;
        if (doRelu) {
            o.x = fmaxf(o.x, 0.f); o.y = fmaxf(o.y, 0.f);
            o.z = fmaxf(o.z, 0.f); o.w = fmaxf(o.w, 0.f);
        }
        ((float4*)(out + (size_t)row * 128))[lane32] = o;
    }
}

// ================= layer 3 (d_out=40, no relu) =================
__global__ __launch_bounds__(320) void k_mm40(const float* __restrict__ agg,
                                              const float* __restrict__ xr,
                                              const float* __restrict__ Wl,
                                              const float* __restrict__ bl,
                                              const float* __restrict__ Wr,
                                              float* __restrict__ out, int n) {
    __shared__ float s_agg[8][128];
    __shared__ float s_x[8][128];
    const int row0 = blockIdx.x * 8;

    for (int idx = threadIdx.x; idx < 8 * 32; idx += 320) {
        const int r = idx >> 5, k4 = idx & 31;
        const int row = row0 + r;
        float4 a = {0.f, 0.f, 0.f, 0.f}, xv = {0.f, 0.f, 0.f, 0.f};
        if (row < n) {
            a  = ((const float4*)(agg + (size_t)row * 128))[k4];
            xv = ((const float4*)(xr  + (size_t)row * 128))[k4];
        }
        ((float4*)s_agg[r])[k4] = a;
        ((float4*)s_x[r])[k4] = xv;
    }
    __syncthreads();

    const int col = threadIdx.x % 40;
    const int r = threadIdx.x / 40;
    float acc = 0.f;
#pragma unroll 4
    for (int k = 0; k < 128; ++k) {
        acc = fmaf(s_agg[r][k], Wl[k * 40 + col], acc);
        acc = fmaf(s_x[r][k], Wr[k * 40 + col], acc);
    }
    const int row = row0 + r;
    if (row < n) out[(size_t)row * 40 + col] = acc + bl[col];
}

extern "C" void kernel_launch(void* const* d_in, const int* in_sizes, int n_in,
                              void* d_out, int out_size, void* d_ws, size_t ws_size,
                              hipStream_t stream) {
    const float* x   = (const float*)d_in[0];
    const int*   ei  = (const int*)d_in[1];
    const float* Wl1 = (const float*)d_in[2];
    const float* bl1 = (const float*)d_in[3];
    const float* Wr1 = (const float*)d_in[4];
    const float* Wl2 = (const float*)d_in[5];
    const float* bl2 = (const float*)d_in[6];
    const float* Wr2 = (const float*)d_in[7];
    const float* Wl3 = (const float*)d_in[8];
    const float* bl3 = (const float*)d_in[9];
    const float* Wr3 = (const float*)d_in[10];
    float* out = (float*)d_out;

    const int N = in_sizes[0] / 128;
    const int E = in_sizes[1] / 2;
    const int* src = ei;
    const int* dst = ei + E;

    auto align1k = [](size_t v) { return (v + 1023) & ~(size_t)1023; };
    const size_t NB = (size_t)N * 128 * sizeof(float);  // 51.2 MB

    char* ws = (char*)d_ws;
    size_t off = 0;
    int* degi     = (int*)(ws + off); off += align1k((size_t)N * 4);        // becomes invdeg (float)
    int* rowptr   = (int*)(ws + off); off += align1k((size_t)(N + 1) * 4);
    int* cursor   = (int*)(ws + off); off += align1k((size_t)N * 4);
    int* partials = (int*)(ws + off); off += align1k(4096);
    int* col      = (int*)(ws + off); off += align1k((size_t)E * 4);
    float* bufA   = (float*)(ws + off); off += NB;
    float* bufB   = (float*)(ws + off);

    const int eBlocks    = idiv_up(E, 256);
    const int nBlocks    = idiv_up(N, 256);
    const int scanBlocks = idiv_up(N, 1024);
    const int aggBlocks  = idiv_up((long)N * 32, 256);
    const int mmBlocks   = idiv_up(N, 64);
    const int mm40Blocks = idiv_up(N, 8);

    // ---- CSR build (once; reused by all 3 layers) ----
    hipMemsetAsync(degi, 0, (size_t)N * sizeof(int), stream);
    hipMemsetAsync(cursor, 0, (size_t)N * sizeof(int), stream);
    k_count<<<eBlocks, 256, 0, stream>>>(dst, degi, E);
    k_scan1<<<scanBlocks, 256, 0, stream>>>(degi, rowptr, partials, N);
    k_scan2<<<1, 256, 0, stream>>>(partials, scanBlocks);
    k_scan3<<<scanBlocks, 256, 0, stream>>>(rowptr, partials, N, E);
    k_invdeg<<<nBlocks, 256, 0, stream>>>(degi, N);  // degi -> invdeg (in place)
    k_fill<<<eBlocks, 256, 0, stream>>>(src, dst, rowptr, cursor, col, E);
    const float* invdeg = (const float*)degi;

    // ---- layer 1: agg(x)->bufA ; h1=relu(agg@Wl1+bl1+x@Wr1)->bufB ----
    k_agg<<<aggBlocks, 256, 0, stream>>>(x, rowptr, col, invdeg, bufA, N);
    k_mm128<<<mmBlocks, 256, 0, stream>>>(bufA, x, Wl1, bl1, Wr1, bufB, N, 1);

    // ---- layer 2: agg(h1)->bufA ; h2 -> bufA (in place) ----
    k_agg<<<aggBlocks, 256, 0, stream>>>(bufB, rowptr, col, invdeg, bufA, N);
    k_mm128<<<mmBlocks, 256, 0, stream>>>(bufA, bufB, Wl2, bl2, Wr2, bufA, N, 1);

    // ---- layer 3: agg(h2)->bufB ; out = agg@Wl3+bl3+h2@Wr3 ----
    k_agg<<<aggBlocks, 256, 0, stream>>>(bufA, rowptr, col, invdeg, bufB, N);
    k_mm40<<<mm40Blocks, 320, 0, stream>>>(bufB, bufA, Wl3, bl3, Wr3, out, N);
}

// Round 3
// 690.382 us; speedup vs baseline: 12.6327x; 1.2223x over previous
//
#include <hip/hip_runtime.h>

static inline int idiv_up(long a, long b) { return (int)((a + b - 1) / b); }

// ================= CSR construction =================

__global__ __launch_bounds__(256) void k_count(const int* __restrict__ dst,
                                               int* __restrict__ degi, int E) {
    int e = blockIdx.x * 256 + threadIdx.x;
    if (e < E) atomicAdd(&degi[dst[e]], 1);
}

__global__ __launch_bounds__(256) void k_invdeg(int* degi, int n) {
    int i = blockIdx.x * 256 + threadIdx.x;
    if (i < n) {
        int d = degi[i];
        ((float*)degi)[i] = 1.0f / fmaxf((float)d, 1.0f);
    }
}

__global__ __launch_bounds__(256) void k_scan1(const int* __restrict__ degi,
                                               int* __restrict__ rowptr,
                                               int* __restrict__ partials, int n) {
    __shared__ int wt[4];
    const int base = blockIdx.x * 1024 + threadIdx.x * 4;
    int v[4];
    int sum = 0;
#pragma unroll
    for (int j = 0; j < 4; ++j) {
        int g = base + j;
        v[j] = (g < n) ? degi[g] : 0;
        sum += v[j];
    }
    const int lane = threadIdx.x & 63;
    const int wid = threadIdx.x >> 6;
    int incl = sum;
    for (int off = 1; off < 64; off <<= 1) {
        int t = __shfl_up(incl, off, 64);
        if (lane >= off) incl += t;
    }
    if (lane == 63) wt[wid] = incl;
    __syncthreads();
    int woff = 0;
    for (int w = 0; w < wid; ++w) woff += wt[w];
    int run = woff + incl - sum;
#pragma unroll
    for (int j = 0; j < 4; ++j) {
        int g = base + j;
        if (g < n) rowptr[g] = run;
        run += v[j];
    }
    if (threadIdx.x == 255) partials[blockIdx.x] = woff + incl;
}

__global__ __launch_bounds__(256) void k_scan2(int* p, int nb) {
    __shared__ int wt[4];
    __shared__ int carry;
    if (threadIdx.x == 0) carry = 0;
    __syncthreads();
    for (int bs = 0; bs < nb; bs += 256) {
        const int i = bs + threadIdx.x;
        int v = (i < nb) ? p[i] : 0;
        const int lane = threadIdx.x & 63;
        const int wid = threadIdx.x >> 6;
        int incl = v;
        for (int off = 1; off < 64; off <<= 1) {
            int t = __shfl_up(incl, off, 64);
            if (lane >= off) incl += t;
        }
        if (lane == 63) wt[wid] = incl;
        __syncthreads();
        int woff = 0;
        for (int w = 0; w < wid; ++w) woff += wt[w];
        int excl = carry + woff + incl - v;
        if (i < nb) p[i] = excl;
        __syncthreads();
        if (threadIdx.x == 255) carry += woff + incl;
        __syncthreads();
    }
}

__global__ __launch_bounds__(256) void k_scan3(int* __restrict__ rowptr,
                                               const int* __restrict__ partials,
                                               int n, int E) {
    const int base = blockIdx.x * 1024;
    const int add = partials[blockIdx.x];
    for (int i = threadIdx.x; i < 1024; i += 256) {
        int g = base + i;
        if (g < n) rowptr[g] += add;
    }
    if (blockIdx.x == 0 && threadIdx.x == 0) rowptr[n] = E;
}

__global__ __launch_bounds__(256) void k_fill(const int* __restrict__ src,
                                              const int* __restrict__ dst,
                                              const int* __restrict__ rowptr,
                                              int* __restrict__ cursor,
                                              int* __restrict__ col, int E) {
    int e = blockIdx.x * 256 + threadIdx.x;
    if (e >= E) return;
    int d = dst[e];
    int pos = rowptr[d] + atomicAdd(&cursor[d], 1);
    col[pos] = src[e];
}

// ================= mean aggregation, d=128 (gather) =================
// 32 lanes per node; lane l owns float4 [4l,4l+4). 4-deep load batching.
__global__ __launch_bounds__(256) void k_agg(const float* __restrict__ x,
                                             const int* __restrict__ rowptr,
                                             const int* __restrict__ col,
                                             const float* __restrict__ invdeg,
                                             float* __restrict__ agg, int n) {
    const int t = blockIdx.x * 256 + threadIdx.x;
    const int node = t >> 5;
    if (node >= n) return;
    const int l = t & 31;
    const int s0 = rowptr[node], s1 = rowptr[node + 1];
    float4 a0 = {0.f, 0.f, 0.f, 0.f};
    float4 a1 = {0.f, 0.f, 0.f, 0.f};
    for (int cb = s0; cb < s1; cb += 32) {
        const int cnt = min(32, s1 - cb);
        const int cc = (cb + l < s1) ? col[cb + l] : 0;
        int j = 0;
        for (; j + 4 <= cnt; j += 4) {
            const int n0 = __shfl(cc, j, 32);
            const int n1 = __shfl(cc, j + 1, 32);
            const int n2 = __shfl(cc, j + 2, 32);
            const int n3 = __shfl(cc, j + 3, 32);
            const float4 v0 = ((const float4*)(x + (size_t)n0 * 128))[l];
            const float4 v1 = ((const float4*)(x + (size_t)n1 * 128))[l];
            const float4 v2 = ((const float4*)(x + (size_t)n2 * 128))[l];
            const float4 v3 = ((const float4*)(x + (size_t)n3 * 128))[l];
            a0.x += v0.x; a0.y += v0.y; a0.z += v0.z; a0.w += v0.w;
            a1.x += v1.x; a1.y += v1.y; a1.z += v1.z; a1.w += v1.w;
            a0.x += v2.x; a0.y += v2.y; a0.z += v2.z; a0.w += v2.w;
            a1.x += v3.x; a1.y += v3.y; a1.z += v3.z; a1.w += v3.w;
        }
        for (; j < cnt; ++j) {
            const int nn = __shfl(cc, j, 32);
            const float4 v = ((const float4*)(x + (size_t)nn * 128))[l];
            a0.x += v.x; a0.y += v.y; a0.z += v.z; a0.w += v.w;
        }
    }
    const float inv = invdeg[node];
    float4 o;
    o.x = (a0.x + a1.x) * inv;
    o.y = (a0.y + a1.y) * inv;
    o.z = (a0.z + a1.z) * inv;
    o.w = (a0.w + a1.w) * inv;
    ((float4*)(agg + (size_t)node * 128))[l] = o;
}

// ================= fused SAGE linear (d_out=128) =================
__global__ __launch_bounds__(256) void k_mm128(const float* agg,
                                               const float* xr_a,
                                               const float* __restrict__ Wl,
                                               const float* __restrict__ bl,
                                               const float* __restrict__ Wr,
                                               float* out, int n, int doRelu) {
    __shared__ float s_agg[64][128];
    __shared__ float s_x[64][128];
    const int row0 = blockIdx.x * 64;

    for (int idx = threadIdx.x; idx < 64 * 32; idx += 256) {
        const int r = idx >> 5, k4 = idx & 31;
        const int row = row0 + r;
        float4 a = {0.f, 0.f, 0.f, 0.f}, xv = {0.f, 0.f, 0.f, 0.f};
        if (row < n) {
            a  = ((const float4*)(agg  + (size_t)row * 128))[k4];
            xv = ((const float4*)(xr_a + (size_t)row * 128))[k4];
        }
        ((float4*)s_agg[r])[k4] = a;
        ((float4*)s_x[r])[k4] = xv;
    }
    __syncthreads();

    const int lane32 = threadIdx.x & 31;
    const int rg = threadIdx.x >> 5;
    const float4* Wl4 = (const float4*)Wl;
    const float4* Wr4 = (const float4*)Wr;

    float4 acc[8];
#pragma unroll
    for (int j = 0; j < 8; ++j) acc[j] = make_float4(0.f, 0.f, 0.f, 0.f);

#pragma unroll 4
    for (int k = 0; k < 128; ++k) {
        const float4 wl = Wl4[k * 32 + lane32];
        const float4 wr = Wr4[k * 32 + lane32];
#pragma unroll
        for (int j = 0; j < 8; ++j) {
            const float a = s_agg[rg * 8 + j][k];
            const float xv = s_x[rg * 8 + j][k];
            acc[j].x = fmaf(a, wl.x, fmaf(xv, wr.x, acc[j].x));
            acc[j].y = fmaf(a, wl.y, fmaf(xv, wr.y, acc[j].y));
            acc[j].z = fmaf(a, wl.z, fmaf(xv, wr.z, acc[j].z));
            acc[j].w = fmaf(a, wl.w, fmaf(xv, wr.w, acc[j].w));
        }
    }

    const float4 bb = ((const float4*)bl)[lane32];
#pragma unroll
    for (int j = 0; j < 8; ++j) {
        const int row = row0 + rg * 8 + j;
        if (row >= n) break;
        float4 o;
        o.x = acc[j].x + bb.x; o.y = acc[j].y + bb.y;
        o.z = acc[j].z + bb.z; o.w = acc[j].w + bb.w;
        if (doRelu) {
            o.x = fmaxf(o.x, 0.f); o.y = fmaxf(o.y, 0.f);
            o.z = fmaxf(o.z, 0.f); o.w = fmaxf(o.w, 0.f);
        }
        ((float4*)(out + (size_t)row * 128))[lane32] = o;
    }
}

// ================= layer 3: t = h2@Wl3, r = h2@Wr3 + bl3 (both N x 40) =======
// 64 rows/block, 320 threads: thread = (col = tid%40, 8 rows), 16 acc chains.
__global__ __launch_bounds__(320) void k_mm_dual40(const float* __restrict__ h,
                                                   const float* __restrict__ Wl,
                                                   const float* __restrict__ Wr,
                                                   const float* __restrict__ bl,
                                                   float* __restrict__ t40,
                                                   float* __restrict__ r40, int n) {
    __shared__ float s_x[64][136];   // pad 136: rows spread across banks
    const int row0 = blockIdx.x * 64;

    for (int idx = threadIdx.x; idx < 64 * 32; idx += 320) {
        const int r = idx >> 5, k4 = idx & 31;
        const int row = row0 + r;
        float4 xv = {0.f, 0.f, 0.f, 0.f};
        if (row < n) xv = ((const float4*)(h + (size_t)row * 128))[k4];
        *(float4*)(&s_x[r][k4 * 4]) = xv;
    }
    __syncthreads();

    const int col = threadIdx.x % 40;
    const int g = threadIdx.x / 40;       // 0..7 -> rows g*8..g*8+7
    float at[8], ar[8];
#pragma unroll
    for (int j = 0; j < 8; ++j) { at[j] = 0.f; ar[j] = 0.f; }

#pragma unroll 4
    for (int k = 0; k < 128; ++k) {
        const float wl = Wl[k * 40 + col];
        const float wr = Wr[k * 40 + col];
#pragma unroll
        for (int j = 0; j < 8; ++j) {
            const float xv = s_x[g * 8 + j][k];
            at[j] = fmaf(xv, wl, at[j]);
            ar[j] = fmaf(xv, wr, ar[j]);
        }
    }

    const float b = bl[col];
#pragma unroll
    for (int j = 0; j < 8; ++j) {
        const int row = row0 + g * 8 + j;
        if (row >= n) break;
        t40[(size_t)row * 40 + col] = at[j];
        r40[(size_t)row * 40 + col] = ar[j] + b;
    }
}

// ================= layer 3 aggregation over d=40: out = invdeg*sum(t[nbr]) + r
// 16 lanes per node; lanes 0..9 own float4 cols.
__global__ __launch_bounds__(256) void k_agg40(const float* __restrict__ t40,
                                               const float* __restrict__ r40,
                                               const int* __restrict__ rowptr,
                                               const int* __restrict__ col,
                                               const float* __restrict__ invdeg,
                                               float* __restrict__ out, int n) {
    const int tt = blockIdx.x * 256 + threadIdx.x;
    const int node = tt >> 4;
    if (node >= n) return;
    const int l = tt & 15;
    const bool act = l < 10;
    const int s0 = rowptr[node], s1 = rowptr[node + 1];
    float4 a0 = {0.f, 0.f, 0.f, 0.f};
    float4 a1 = {0.f, 0.f, 0.f, 0.f};
    for (int cb = s0; cb < s1; cb += 16) {
        const int cnt = min(16, s1 - cb);
        const int cc = (cb + l < s1) ? col[cb + l] : 0;
        int j = 0;
        for (; j + 4 <= cnt; j += 4) {
            const int n0 = __shfl(cc, j, 16);
            const int n1 = __shfl(cc, j + 1, 16);
            const int n2 = __shfl(cc, j + 2, 16);
            const int n3 = __shfl(cc, j + 3, 16);
            if (act) {
                const float4 v0 = *(const float4*)(t40 + (size_t)n0 * 40 + 4 * l);
                const float4 v1 = *(const float4*)(t40 + (size_t)n1 * 40 + 4 * l);
                const float4 v2 = *(const float4*)(t40 + (size_t)n2 * 40 + 4 * l);
                const float4 v3 = *(const float4*)(t40 + (size_t)n3 * 40 + 4 * l);
                a0.x += v0.x; a0.y += v0.y; a0.z += v0.z; a0.w += v0.w;
                a1.x += v1.x; a1.y += v1.y; a1.z += v1.z; a1.w += v1.w;
                a0.x += v2.x; a0.y += v2.y; a0.z += v2.z; a0.w += v2.w;
                a1.x += v3.x; a1.y += v3.y; a1.z += v3.z; a1.w += v3.w;
            }
        }
        for (; j < cnt; ++j) {
            const int nn = __shfl(cc, j, 16);
            if (act) {
                const float4 v = *(const float4*)(t40 + (size_t)nn * 40 + 4 * l);
                a0.x += v.x; a0.y += v.y; a0.z += v.z; a0.w += v.w;
            }
        }
    }
    if (act) {
        const float inv = invdeg[node];
        const float4 rv = *(const float4*)(r40 + (size_t)node * 40 + 4 * l);
        float4 o;
        o.x = fmaf(a0.x + a1.x, inv, rv.x);
        o.y = fmaf(a0.y + a1.y, inv, rv.y);
        o.z = fmaf(a0.z + a1.z, inv, rv.z);
        o.w = fmaf(a0.w + a1.w, inv, rv.w);
        *(float4*)(out + (size_t)node * 40 + 4 * l) = o;
    }
}

extern "C" void kernel_launch(void* const* d_in, const int* in_sizes, int n_in,
                              void* d_out, int out_size, void* d_ws, size_t ws_size,
                              hipStream_t stream) {
    const float* x   = (const float*)d_in[0];
    const int*   ei  = (const int*)d_in[1];
    const float* Wl1 = (const float*)d_in[2];
    const float* bl1 = (const float*)d_in[3];
    const float* Wr1 = (const float*)d_in[4];
    const float* Wl2 = (const float*)d_in[5];
    const float* bl2 = (const float*)d_in[6];
    const float* Wr2 = (const float*)d_in[7];
    const float* Wl3 = (const float*)d_in[8];
    const float* bl3 = (const float*)d_in[9];
    const float* Wr3 = (const float*)d_in[10];
    float* out = (float*)d_out;

    const int N = in_sizes[0] / 128;
    const int E = in_sizes[1] / 2;
    const int* src = ei;
    const int* dst = ei + E;

    auto align1k = [](size_t v) { return (v + 1023) & ~(size_t)1023; };
    const size_t NB = (size_t)N * 128 * sizeof(float);

    char* ws = (char*)d_ws;
    size_t off = 0;
    int* degi     = (int*)(ws + off); off += align1k((size_t)N * 4);
    int* rowptr   = (int*)(ws + off); off += align1k((size_t)(N + 1) * 4);
    int* cursor   = (int*)(ws + off); off += align1k((size_t)N * 4);
    int* partials = (int*)(ws + off); off += align1k(4096);
    int* col      = (int*)(ws + off); off += align1k((size_t)E * 4);
    float* bufA   = (float*)(ws + off); off += NB;
    float* bufB   = (float*)(ws + off);
    float* t40 = bufB;
    float* r40 = bufB + (size_t)N * 40;

    const int eBlocks    = idiv_up(E, 256);
    const int nBlocks    = idiv_up(N, 256);
    const int scanBlocks = idiv_up(N, 1024);
    const int aggBlocks  = idiv_up((long)N * 32, 256);
    const int agg40Blk   = idiv_up((long)N * 16, 256);
    const int mmBlocks   = idiv_up(N, 64);

    // ---- CSR build ----
    hipMemsetAsync(degi, 0, (size_t)N * sizeof(int), stream);
    hipMemsetAsync(cursor, 0, (size_t)N * sizeof(int), stream);
    k_count<<<eBlocks, 256, 0, stream>>>(dst, degi, E);
    k_scan1<<<scanBlocks, 256, 0, stream>>>(degi, rowptr, partials, N);
    k_scan2<<<1, 256, 0, stream>>>(partials, scanBlocks);
    k_scan3<<<scanBlocks, 256, 0, stream>>>(rowptr, partials, N, E);
    k_invdeg<<<nBlocks, 256, 0, stream>>>(degi, N);
    k_fill<<<eBlocks, 256, 0, stream>>>(src, dst, rowptr, cursor, col, E);
    const float* invdeg = (const float*)degi;

    // ---- layer 1 ----
    k_agg<<<aggBlocks, 256, 0, stream>>>(x, rowptr, col, invdeg, bufA, N);
    k_mm128<<<mmBlocks, 256, 0, stream>>>(bufA, x, Wl1, bl1, Wr1, bufB, N, 1);

    // ---- layer 2 (h2 -> bufA in place over agg) ----
    k_agg<<<aggBlocks, 256, 0, stream>>>(bufB, rowptr, col, invdeg, bufA, N);
    k_mm128<<<mmBlocks, 256, 0, stream>>>(bufA, bufB, Wl2, bl2, Wr2, bufA, N, 1);

    // ---- layer 3: transform-then-aggregate over d=40 ----
    k_mm_dual40<<<mmBlocks, 320, 0, stream>>>(bufA, Wl3, Wr3, bl3, t40, r40, N);
    k_agg40<<<agg40Blk, 256, 0, stream>>>(t40, r40, rowptr, col, invdeg, out, N);
}

// Round 4
// 573.794 us; speedup vs baseline: 15.1995x; 1.2032x over previous
//
#include <hip/hip_runtime.h>

using u16 = unsigned short;
using u32 = unsigned int;

static inline int idiv_up(long a, long b) { return (int)((a + b - 1) / b); }

// ---------- bf16 helpers (packed pairs in u32, elem0 = low half) ----------
__device__ __forceinline__ float bflo(u32 p) { return __uint_as_float(p << 16); }
__device__ __forceinline__ float bfhi(u32 p) { return __uint_as_float(p & 0xffff0000u); }
__device__ __forceinline__ u32 f2bf1(float f) {
    u32 x = __float_as_uint(f);
    return (x + 0x7fffu + ((x >> 16) & 1u)) >> 16;   // RNE
}
__device__ __forceinline__ u32 pack2(float lo, float hi) {
    return f2bf1(lo) | (f2bf1(hi) << 16);
}

// ================= cast x (fp32) -> xb (bf16) =================
__global__ __launch_bounds__(256) void k_cast(const float* __restrict__ x,
                                              u32* __restrict__ xb, long nelem) {
    long i = ((long)blockIdx.x * 256 + threadIdx.x) * 8;
    if (i >= nelem) return;
    float4 v0 = *(const float4*)(x + i);
    float4 v1 = *(const float4*)(x + i + 4);
    uint4 o;
    o.x = pack2(v0.x, v0.y);
    o.y = pack2(v0.z, v0.w);
    o.z = pack2(v1.x, v1.y);
    o.w = pack2(v1.z, v1.w);
    *(uint4*)(xb + (i >> 1)) = o;
}

// ================= CSR construction =================
__global__ __launch_bounds__(256) void k_count(const int* __restrict__ dst,
                                               int* __restrict__ degi, int E) {
    int e = blockIdx.x * 256 + threadIdx.x;
    if (e < E) atomicAdd(&degi[dst[e]], 1);
}

// scan over degrees; also emits invd = 1/max(deg,1)
__global__ __launch_bounds__(256) void k_scan1(const int* __restrict__ degi,
                                               int* __restrict__ rowptr,
                                               float* __restrict__ invd,
                                               int* __restrict__ partials, int n) {
    __shared__ int wt[4];
    const int base = blockIdx.x * 1024 + threadIdx.x * 4;
    int v[4];
    int sum = 0;
#pragma unroll
    for (int j = 0; j < 4; ++j) {
        int g = base + j;
        v[j] = (g < n) ? degi[g] : 0;
        sum += v[j];
    }
    const int lane = threadIdx.x & 63;
    const int wid = threadIdx.x >> 6;
    int incl = sum;
    for (int off = 1; off < 64; off <<= 1) {
        int t = __shfl_up(incl, off, 64);
        if (lane >= off) incl += t;
    }
    if (lane == 63) wt[wid] = incl;
    __syncthreads();
    int woff = 0;
    for (int w = 0; w < wid; ++w) woff += wt[w];
    int run = woff + incl - sum;
#pragma unroll
    for (int j = 0; j < 4; ++j) {
        int g = base + j;
        if (g < n) {
            rowptr[g] = run;
            invd[g] = 1.0f / fmaxf((float)v[j], 1.0f);
        }
        run += v[j];
    }
    if (threadIdx.x == 255) partials[blockIdx.x] = woff + incl;
}

__global__ __launch_bounds__(256) void k_scan2(int* p, int nb) {
    __shared__ int wt[4];
    __shared__ int carry;
    if (threadIdx.x == 0) carry = 0;
    __syncthreads();
    for (int bs = 0; bs < nb; bs += 256) {
        const int i = bs + threadIdx.x;
        int v = (i < nb) ? p[i] : 0;
        const int lane = threadIdx.x & 63;
        const int wid = threadIdx.x >> 6;
        int incl = v;
        for (int off = 1; off < 64; off <<= 1) {
            int t = __shfl_up(incl, off, 64);
            if (lane >= off) incl += t;
        }
        if (lane == 63) wt[wid] = incl;
        __syncthreads();
        int woff = 0;
        for (int w = 0; w < wid; ++w) woff += wt[w];
        int excl = carry + woff + incl - v;
        if (i < nb) p[i] = excl;
        __syncthreads();
        if (threadIdx.x == 255) carry += woff + incl;
        __syncthreads();
    }
}

__global__ __launch_bounds__(256) void k_scan3(int* __restrict__ rowptr,
                                               const int* __restrict__ partials,
                                               int n, int E) {
    const int base = blockIdx.x * 1024;
    const int add = partials[blockIdx.x];
    for (int i = threadIdx.x; i < 1024; i += 256) {
        int g = base + i;
        if (g < n) rowptr[g] += add;
    }
    if (blockIdx.x == 0 && threadIdx.x == 0) rowptr[n] = E;
}

// fill backward: degi acts as per-node down-counter (consumed; re-zeroed -> recounted each call)
__global__ __launch_bounds__(256) void k_fill(const int* __restrict__ src,
                                              const int* __restrict__ dst,
                                              const int* __restrict__ rowptr,
                                              int* __restrict__ degi,
                                              int* __restrict__ col, int E) {
    int e = blockIdx.x * 256 + threadIdx.x;
    if (e >= E) return;
    int d = dst[e];
    int old = atomicAdd(&degi[d], -1);
    col[rowptr[d] + old - 1] = src[e];
}

// ================= mean aggregation, d=128, bf16 in / bf16 out =================
// 32 lanes per node; lane l owns elems [4l,4l+4) (one uint2 = 8 B per neighbor).
#define ACC4(A, V)                                                     \
    A.x += bflo(V.x); A.y += bfhi(V.x); A.z += bflo(V.y); A.w += bfhi(V.y);

__global__ __launch_bounds__(256) void k_aggb(const u16* __restrict__ xb,
                                              const int* __restrict__ rowptr,
                                              const int* __restrict__ col,
                                              const float* __restrict__ invd,
                                              u16* __restrict__ aggb, int n) {
    const int t = blockIdx.x * 256 + threadIdx.x;
    const int node = t >> 5;
    if (node >= n) return;
    const int l = t & 31;
    const int s0 = rowptr[node], s1 = rowptr[node + 1];
    float4 a0 = {0.f, 0.f, 0.f, 0.f};
    float4 a1 = {0.f, 0.f, 0.f, 0.f};
    for (int cb = s0; cb < s1; cb += 32) {
        const int cnt = min(32, s1 - cb);
        const int cc = (cb + l < s1) ? col[cb + l] : 0;
        int j = 0;
        for (; j + 8 <= cnt; j += 8) {
            const int n0 = __shfl(cc, j, 32);
            const int n1 = __shfl(cc, j + 1, 32);
            const int n2 = __shfl(cc, j + 2, 32);
            const int n3 = __shfl(cc, j + 3, 32);
            const int n4 = __shfl(cc, j + 4, 32);
            const int n5 = __shfl(cc, j + 5, 32);
            const int n6 = __shfl(cc, j + 6, 32);
            const int n7 = __shfl(cc, j + 7, 32);
            const uint2 v0 = *(const uint2*)(xb + (size_t)n0 * 128 + 4 * l);
            const uint2 v1 = *(const uint2*)(xb + (size_t)n1 * 128 + 4 * l);
            const uint2 v2 = *(const uint2*)(xb + (size_t)n2 * 128 + 4 * l);
            const uint2 v3 = *(const uint2*)(xb + (size_t)n3 * 128 + 4 * l);
            const uint2 v4 = *(const uint2*)(xb + (size_t)n4 * 128 + 4 * l);
            const uint2 v5 = *(const uint2*)(xb + (size_t)n5 * 128 + 4 * l);
            const uint2 v6 = *(const uint2*)(xb + (size_t)n6 * 128 + 4 * l);
            const uint2 v7 = *(const uint2*)(xb + (size_t)n7 * 128 + 4 * l);
            ACC4(a0, v0); ACC4(a1, v1); ACC4(a0, v2); ACC4(a1, v3);
            ACC4(a0, v4); ACC4(a1, v5); ACC4(a0, v6); ACC4(a1, v7);
        }
        for (; j + 4 <= cnt; j += 4) {
            const int n0 = __shfl(cc, j, 32);
            const int n1 = __shfl(cc, j + 1, 32);
            const int n2 = __shfl(cc, j + 2, 32);
            const int n3 = __shfl(cc, j + 3, 32);
            const uint2 v0 = *(const uint2*)(xb + (size_t)n0 * 128 + 4 * l);
            const uint2 v1 = *(const uint2*)(xb + (size_t)n1 * 128 + 4 * l);
            const uint2 v2 = *(const uint2*)(xb + (size_t)n2 * 128 + 4 * l);
            const uint2 v3 = *(const uint2*)(xb + (size_t)n3 * 128 + 4 * l);
            ACC4(a0, v0); ACC4(a1, v1); ACC4(a0, v2); ACC4(a1, v3);
        }
        for (; j < cnt; ++j) {
            const int nn = __shfl(cc, j, 32);
            const uint2 v = *(const uint2*)(xb + (size_t)nn * 128 + 4 * l);
            ACC4(a0, v);
        }
    }
    const float inv = invd[node];
    uint2 o;
    o.x = pack2((a0.x + a1.x) * inv, (a0.y + a1.y) * inv);
    o.y = pack2((a0.z + a1.z) * inv, (a0.w + a1.w) * inv);
    *(uint2*)(aggb + (size_t)node * 128 + 4 * l) = o;
}

// ================= fused SAGE linear (d_out=128), bf16 in/out, relu ==========
__global__ __launch_bounds__(256) void k_mm128b(const u16* __restrict__ aggb,
                                                const u16* __restrict__ xrb,
                                                const float* __restrict__ Wl,
                                                const float* __restrict__ bl,
                                                const float* __restrict__ Wr,
                                                u16* __restrict__ outb, int n) {
    __shared__ float s_agg[64][128];
    __shared__ float s_x[64][128];
    const int row0 = blockIdx.x * 64;

    for (int idx = threadIdx.x; idx < 64 * 16; idx += 256) {
        const int r = idx >> 4, c = idx & 15;   // 8-elem chunk
        const int row = row0 + r;
        uint4 av = {0u, 0u, 0u, 0u}, xv = {0u, 0u, 0u, 0u};
        if (row < n) {
            av = *(const uint4*)(aggb + (size_t)row * 128 + c * 8);
            xv = *(const uint4*)(xrb  + (size_t)row * 128 + c * 8);
        }
        float* sa = &s_agg[r][c * 8];
        sa[0] = bflo(av.x); sa[1] = bfhi(av.x); sa[2] = bflo(av.y); sa[3] = bfhi(av.y);
        sa[4] = bflo(av.z); sa[5] = bfhi(av.z); sa[6] = bflo(av.w); sa[7] = bfhi(av.w);
        float* sx = &s_x[r][c * 8];
        sx[0] = bflo(xv.x); sx[1] = bfhi(xv.x); sx[2] = bflo(xv.y); sx[3] = bfhi(xv.y);
        sx[4] = bflo(xv.z); sx[5] = bfhi(xv.z); sx[6] = bflo(xv.w); sx[7] = bfhi(xv.w);
    }
    __syncthreads();

    const int lane32 = threadIdx.x & 31;
    const int rg = threadIdx.x >> 5;
    const float4* Wl4 = (const float4*)Wl;
    const float4* Wr4 = (const float4*)Wr;

    float4 acc[8];
#pragma unroll
    for (int j = 0; j < 8; ++j) acc[j] = make_float4(0.f, 0.f, 0.f, 0.f);

#pragma unroll 4
    for (int k = 0; k < 128; ++k) {
        const float4 wl = Wl4[k * 32 + lane32];
        const float4 wr = Wr4[k * 32 + lane32];
#pragma unroll
        for (int j = 0; j < 8; ++j) {
            const float a = s_agg[rg * 8 + j][k];
            const float xv = s_x[rg * 8 + j][k];
            acc[j].x = fmaf(a, wl.x, fmaf(xv, wr.x, acc[j].x));
            acc[j].y = fmaf(a, wl.y, fmaf(xv, wr.y, acc[j].y));
            acc[j].z = fmaf(a, wl.z, fmaf(xv, wr.z, acc[j].z));
            acc[j].w = fmaf(a, wl.w, fmaf(xv, wr.w, acc[j].w));
        }
    }

    const float4 bb = ((const float4*)bl)[lane32];
#pragma unroll
    for (int j = 0; j < 8; ++j) {
        const int row = row0 + rg * 8 + j;
        if (row >= n) break;
        float ox = fmaxf(acc[j].x + bb.x, 0.f);
        float oy = fmaxf(acc[j].y + bb.y, 0.f);
        float oz = fmaxf(acc[j].z + bb.z, 0.f);
        float ow = fmaxf(acc[j].w + bb.w, 0.f);
        uint2 o;
        o.x = pack2(ox, oy);
        o.y = pack2(oz, ow);
        *(uint2*)(outb + (size_t)row * 128 + 4 * lane32) = o;
    }
}

// ================= layer 3: t = h2@Wl3 (bf16 out), r = h2@Wr3 + bl3 (fp32) ===
__global__ __launch_bounds__(320) void k_dual40(const u16* __restrict__ hb,
                                                const float* __restrict__ Wl,
                                                const float* __restrict__ Wr,
                                                const float* __restrict__ bl,
                                                u16* __restrict__ t40b,
                                                float* __restrict__ r40, int n) {
    __shared__ float s_x[64][136];
    const int row0 = blockIdx.x * 64;

    for (int idx = threadIdx.x; idx < 64 * 16; idx += 320) {
        const int r = idx >> 4, c = idx & 15;
        const int row = row0 + r;
        uint4 xv = {0u, 0u, 0u, 0u};
        if (row < n) xv = *(const uint4*)(hb + (size_t)row * 128 + c * 8);
        float* sx = &s_x[r][c * 8];
        sx[0] = bflo(xv.x); sx[1] = bfhi(xv.x); sx[2] = bflo(xv.y); sx[3] = bfhi(xv.y);
        sx[4] = bflo(xv.z); sx[5] = bfhi(xv.z); sx[6] = bflo(xv.w); sx[7] = bfhi(xv.w);
    }
    __syncthreads();

    const int col = threadIdx.x % 40;
    const int g = threadIdx.x / 40;
    float at[8], ar[8];
#pragma unroll
    for (int j = 0; j < 8; ++j) { at[j] = 0.f; ar[j] = 0.f; }

#pragma unroll 4
    for (int k = 0; k < 128; ++k) {
        const float wl = Wl[k * 40 + col];
        const float wr = Wr[k * 40 + col];
#pragma unroll
        for (int j = 0; j < 8; ++j) {
            const float xv = s_x[g * 8 + j][k];
            at[j] = fmaf(xv, wl, at[j]);
            ar[j] = fmaf(xv, wr, ar[j]);
        }
    }

    const float b = bl[col];
#pragma unroll
    for (int j = 0; j < 8; ++j) {
        const int row = row0 + g * 8 + j;
        if (row >= n) break;
        t40b[(size_t)row * 40 + col] = (u16)f2bf1(at[j]);
        r40[(size_t)row * 40 + col] = ar[j] + b;
    }
}

// ================= layer 3 aggregation (d=40): out = invd*sum(t[nbr]) + r ====
// 16 lanes per node; lanes 0..9 each own 4 cols (uint2 = 4 bf16).
__global__ __launch_bounds__(256) void k_agg40(const u16* __restrict__ t40b,
                                               const float* __restrict__ r40,
                                               const int* __restrict__ rowptr,
                                               const int* __restrict__ col,
                                               const float* __restrict__ invd,
                                               float* __restrict__ out, int n) {
    const int tt = blockIdx.x * 256 + threadIdx.x;
    const int node = tt >> 4;
    if (node >= n) return;
    const int l = tt & 15;
    const bool act = l < 10;
    const int s0 = rowptr[node], s1 = rowptr[node + 1];
    float4 a0 = {0.f, 0.f, 0.f, 0.f};
    float4 a1 = {0.f, 0.f, 0.f, 0.f};
    for (int cb = s0; cb < s1; cb += 16) {
        const int cnt = min(16, s1 - cb);
        const int cc = (cb + l < s1) ? col[cb + l] : 0;
        int j = 0;
        for (; j + 4 <= cnt; j += 4) {
            const int n0 = __shfl(cc, j, 16);
            const int n1 = __shfl(cc, j + 1, 16);
            const int n2 = __shfl(cc, j + 2, 16);
            const int n3 = __shfl(cc, j + 3, 16);
            if (act) {
                const uint2 v0 = *(const uint2*)(t40b + (size_t)n0 * 40 + 4 * l);
                const uint2 v1 = *(const uint2*)(t40b + (size_t)n1 * 40 + 4 * l);
                const uint2 v2 = *(const uint2*)(t40b + (size_t)n2 * 40 + 4 * l);
                const uint2 v3 = *(const uint2*)(t40b + (size_t)n3 * 40 + 4 * l);
                ACC4(a0, v0); ACC4(a1, v1); ACC4(a0, v2); ACC4(a1, v3);
            }
        }
        for (; j < cnt; ++j) {
            const int nn = __shfl(cc, j, 16);
            if (act) {
                const uint2 v = *(const uint2*)(t40b + (size_t)nn * 40 + 4 * l);
                ACC4(a0, v);
            }
        }
    }
    if (act) {
        const float inv = invd[node];
        const float4 rv = *(const float4*)(r40 + (size_t)node * 40 + 4 * l);
        float4 o;
        o.x = fmaf(a0.x + a1.x, inv, rv.x);
        o.y = fmaf(a0.y + a1.y, inv, rv.y);
        o.z = fmaf(a0.z + a1.z, inv, rv.z);
        o.w = fmaf(a0.w + a1.w, inv, rv.w);
        *(float4*)(out + (size_t)node * 40 + 4 * l) = o;
    }
}

extern "C" void kernel_launch(void* const* d_in, const int* in_sizes, int n_in,
                              void* d_out, int out_size, void* d_ws, size_t ws_size,
                              hipStream_t stream) {
    const float* x   = (const float*)d_in[0];
    const int*   ei  = (const int*)d_in[1];
    const float* Wl1 = (const float*)d_in[2];
    const float* bl1 = (const float*)d_in[3];
    const float* Wr1 = (const float*)d_in[4];
    const float* Wl2 = (const float*)d_in[5];
    const float* bl2 = (const float*)d_in[6];
    const float* Wr2 = (const float*)d_in[7];
    const float* Wl3 = (const float*)d_in[8];
    const float* bl3 = (const float*)d_in[9];
    const float* Wr3 = (const float*)d_in[10];
    float* out = (float*)d_out;

    const int N = in_sizes[0] / 128;
    const int E = in_sizes[1] / 2;
    const int* src = ei;
    const int* dst = ei + E;

    auto align1k = [](size_t v) { return (v + 1023) & ~(size_t)1023; };
    const size_t NB16 = (size_t)N * 128 * sizeof(u16);   // 25.6 MB

    char* ws = (char*)d_ws;
    size_t off = 0;
    int*   degi     = (int*)(ws + off);   off += align1k((size_t)N * 4);
    float* invd     = (float*)(ws + off); off += align1k((size_t)N * 4);
    int*   rowptr   = (int*)(ws + off);   off += align1k((size_t)(N + 1) * 4);
    int*   partials = (int*)(ws + off);   off += align1k(4096);
    int*   col      = (int*)(ws + off);   off += align1k((size_t)E * 4);
    u16*   aggb     = (u16*)(ws + off);   off += align1k(NB16);
    u16*   xb       = (u16*)(ws + off);   off += align1k(NB16);   // later: h2b
    char*  regionY  = (ws + off);         off += align1k(NB16);   // h1b, later t40b+r40
    u16*   h1b  = (u16*)regionY;
    u16*   h2b  = xb;                                     // xb dead after L1 mm
    u16*   t40b = (u16*)regionY;                          // h1b dead after L2 mm
    float* r40  = (float*)(regionY + align1k((size_t)N * 40 * sizeof(u16)));

    const int eBlocks    = idiv_up(E, 256);
    const int scanBlocks = idiv_up(N, 1024);
    const int castBlocks = idiv_up((long)N * 128, 2048);
    const int aggBlocks  = idiv_up((long)N * 32, 256);
    const int agg40Blk   = idiv_up((long)N * 16, 256);
    const int mmBlocks   = idiv_up(N, 64);

    // ---- cast x -> bf16 ----
    k_cast<<<castBlocks, 256, 0, stream>>>(x, (u32*)xb, (long)N * 128);

    // ---- CSR build ----
    hipMemsetAsync(degi, 0, (size_t)N * sizeof(int), stream);
    k_count<<<eBlocks, 256, 0, stream>>>(dst, degi, E);
    k_scan1<<<scanBlocks, 256, 0, stream>>>(degi, rowptr, invd, partials, N);
    k_scan2<<<1, 256, 0, stream>>>(partials, scanBlocks);
    k_scan3<<<scanBlocks, 256, 0, stream>>>(rowptr, partials, N, E);
    k_fill<<<eBlocks, 256, 0, stream>>>(src, dst, rowptr, degi, col, E);

    // ---- layer 1 ----
    k_aggb<<<aggBlocks, 256, 0, stream>>>(xb, rowptr, col, invd, aggb, N);
    k_mm128b<<<mmBlocks, 256, 0, stream>>>(aggb, xb, Wl1, bl1, Wr1, h1b, N);

    // ---- layer 2 ----
    k_aggb<<<aggBlocks, 256, 0, stream>>>(h1b, rowptr, col, invd, aggb, N);
    k_mm128b<<<mmBlocks, 256, 0, stream>>>(aggb, h1b, Wl2, bl2, Wr2, h2b, N);

    // ---- layer 3: transform-then-aggregate over d=40 ----
    k_dual40<<<mmBlocks, 320, 0, stream>>>(h2b, Wl3, Wr3, bl3, t40b, r40, N);
    k_agg40<<<agg40Blk, 256, 0, stream>>>(t40b, r40, rowptr, col, invd, out, N);
}

// Round 5
// 548.997 us; speedup vs baseline: 15.8860x; 1.0452x over previous
//
#include <hip/hip_runtime.h>

using u16 = unsigned short;
using u32 = unsigned int;

static inline int idiv_up(long a, long b) { return (int)((a + b - 1) / b); }

// ---------- bf16 helpers (packed pairs in u32, elem0 = low half) ----------
__device__ __forceinline__ float bflo(u32 p) { return __uint_as_float(p << 16); }
__device__ __forceinline__ float bfhi(u32 p) { return __uint_as_float(p & 0xffff0000u); }
__device__ __forceinline__ u32 f2bf1(float f) {
    u32 x = __float_as_uint(f);
    return (x + 0x7fffu + ((x >> 16) & 1u)) >> 16;   // RNE
}
__device__ __forceinline__ u32 pack2(float lo, float hi) {
    return f2bf1(lo) | (f2bf1(hi) << 16);
}

// ================= cast x (fp32) -> xb (bf16) =================
__global__ __launch_bounds__(256) void k_cast(const float* __restrict__ x,
                                              u32* __restrict__ xb, long nelem) {
    long i = ((long)blockIdx.x * 256 + threadIdx.x) * 8;
    if (i >= nelem) return;
    float4 v0 = *(const float4*)(x + i);
    float4 v1 = *(const float4*)(x + i + 4);
    uint4 o;
    o.x = pack2(v0.x, v0.y);
    o.y = pack2(v0.z, v0.w);
    o.z = pack2(v1.x, v1.y);
    o.w = pack2(v1.z, v1.w);
    *(uint4*)(xb + (i >> 1)) = o;
}

// ================= CSR construction =================
__global__ __launch_bounds__(256) void k_count(const int* __restrict__ dst,
                                               int* __restrict__ degi, int E) {
    int e = blockIdx.x * 256 + threadIdx.x;
    if (e < E) atomicAdd(&degi[__builtin_nontemporal_load(&dst[e])], 1);
}

// scan over degrees; also emits invd = 1/max(deg,1)
__global__ __launch_bounds__(256) void k_scan1(const int* __restrict__ degi,
                                               int* __restrict__ rowptr,
                                               float* __restrict__ invd,
                                               int* __restrict__ partials, int n) {
    __shared__ int wt[4];
    const int base = blockIdx.x * 1024 + threadIdx.x * 4;
    int v[4];
    int sum = 0;
#pragma unroll
    for (int j = 0; j < 4; ++j) {
        int g = base + j;
        v[j] = (g < n) ? degi[g] : 0;
        sum += v[j];
    }
    const int lane = threadIdx.x & 63;
    const int wid = threadIdx.x >> 6;
    int incl = sum;
    for (int off = 1; off < 64; off <<= 1) {
        int t = __shfl_up(incl, off, 64);
        if (lane >= off) incl += t;
    }
    if (lane == 63) wt[wid] = incl;
    __syncthreads();
    int woff = 0;
    for (int w = 0; w < wid; ++w) woff += wt[w];
    int run = woff + incl - sum;
#pragma unroll
    for (int j = 0; j < 4; ++j) {
        int g = base + j;
        if (g < n) {
            rowptr[g] = run;
            invd[g] = 1.0f / fmaxf((float)v[j], 1.0f);
        }
        run += v[j];
    }
    if (threadIdx.x == 255) partials[blockIdx.x] = woff + incl;
}

__global__ __launch_bounds__(256) void k_scan2(int* p, int nb) {
    __shared__ int wt[4];
    __shared__ int carry;
    if (threadIdx.x == 0) carry = 0;
    __syncthreads();
    for (int bs = 0; bs < nb; bs += 256) {
        const int i = bs + threadIdx.x;
        int v = (i < nb) ? p[i] : 0;
        const int lane = threadIdx.x & 63;
        const int wid = threadIdx.x >> 6;
        int incl = v;
        for (int off = 1; off < 64; off <<= 1) {
            int t = __shfl_up(incl, off, 64);
            if (lane >= off) incl += t;
        }
        if (lane == 63) wt[wid] = incl;
        __syncthreads();
        int woff = 0;
        for (int w = 0; w < wid; ++w) woff += wt[w];
        int excl = carry + woff + incl - v;
        if (i < nb) p[i] = excl;
        __syncthreads();
        if (threadIdx.x == 255) carry += woff + incl;
        __syncthreads();
    }
}

__global__ __launch_bounds__(256) void k_scan3(int* __restrict__ rowptr,
                                               const int* __restrict__ partials,
                                               int n, int E) {
    const int base = blockIdx.x * 1024;
    const int add = partials[blockIdx.x];
    for (int i = threadIdx.x; i < 1024; i += 256) {
        int g = base + i;
        if (g < n) rowptr[g] += add;
    }
    if (blockIdx.x == 0 && threadIdx.x == 0) rowptr[n] = E;
}

// Partitioned fill: 8 dst-range groups; group g = blockIdx&7 (lands on one XCD
// under round-robin dispatch -> its 0.8 MB col region stays L2-resident and
// each 64B line collects all its writes before one writeback). degi is a
// per-node down-counter (consumed to zero; recounted every launch).
#define FILL_BPG 128
__global__ __launch_bounds__(256) void k_fillp(const int* __restrict__ src,
                                               const int* __restrict__ dst,
                                               const int* __restrict__ rowptr,
                                               int* __restrict__ degi,
                                               int* __restrict__ col,
                                               int E, int rangeSize) {
    const int g = blockIdx.x & 7;
    const int b = blockIdx.x >> 3;
    const int lo = g * rangeSize;
    const int hi = lo + rangeSize;   // dst < N <= 8*rangeSize always
    const long chunk = (E + FILL_BPG - 1) / FILL_BPG;
    const long e0 = (long)b * chunk;
    const long e1 = (e0 + chunk < (long)E) ? e0 + chunk : (long)E;
    for (long e = e0 + threadIdx.x; e < e1; e += 256) {
        const int d = __builtin_nontemporal_load(&dst[e]);
        if (d >= lo && d < hi) {
            const int s = __builtin_nontemporal_load(&src[e]);
            const int old = atomicAdd(&degi[d], -1);
            col[rowptr[d] + old - 1] = s;
        }
    }
}

// ================= mean aggregation, d=128, bf16 in / bf16 out =================
#define ACC4(A, V)                                                     \
    A.x += bflo(V.x); A.y += bfhi(V.x); A.z += bflo(V.y); A.w += bfhi(V.y);

__global__ __launch_bounds__(256) void k_aggb(const u16* __restrict__ xb,
                                              const int* __restrict__ rowptr,
                                              const int* __restrict__ col,
                                              const float* __restrict__ invd,
                                              u16* __restrict__ aggb, int n) {
    const int t = blockIdx.x * 256 + threadIdx.x;
    const int node = t >> 5;
    if (node >= n) return;
    const int l = t & 31;
    const int s0 = rowptr[node], s1 = rowptr[node + 1];
    float4 a0 = {0.f, 0.f, 0.f, 0.f};
    float4 a1 = {0.f, 0.f, 0.f, 0.f};
    for (int cb = s0; cb < s1; cb += 32) {
        const int cnt = min(32, s1 - cb);
        const int cc = (cb + l < s1) ? col[cb + l] : 0;
        int j = 0;
        for (; j + 8 <= cnt; j += 8) {
            const int n0 = __shfl(cc, j, 32);
            const int n1 = __shfl(cc, j + 1, 32);
            const int n2 = __shfl(cc, j + 2, 32);
            const int n3 = __shfl(cc, j + 3, 32);
            const int n4 = __shfl(cc, j + 4, 32);
            const int n5 = __shfl(cc, j + 5, 32);
            const int n6 = __shfl(cc, j + 6, 32);
            const int n7 = __shfl(cc, j + 7, 32);
            const uint2 v0 = *(const uint2*)(xb + (size_t)n0 * 128 + 4 * l);
            const uint2 v1 = *(const uint2*)(xb + (size_t)n1 * 128 + 4 * l);
            const uint2 v2 = *(const uint2*)(xb + (size_t)n2 * 128 + 4 * l);
            const uint2 v3 = *(const uint2*)(xb + (size_t)n3 * 128 + 4 * l);
            const uint2 v4 = *(const uint2*)(xb + (size_t)n4 * 128 + 4 * l);
            const uint2 v5 = *(const uint2*)(xb + (size_t)n5 * 128 + 4 * l);
            const uint2 v6 = *(const uint2*)(xb + (size_t)n6 * 128 + 4 * l);
            const uint2 v7 = *(const uint2*)(xb + (size_t)n7 * 128 + 4 * l);
            ACC4(a0, v0); ACC4(a1, v1); ACC4(a0, v2); ACC4(a1, v3);
            ACC4(a0, v4); ACC4(a1, v5); ACC4(a0, v6); ACC4(a1, v7);
        }
        for (; j + 4 <= cnt; j += 4) {
            const int n0 = __shfl(cc, j, 32);
            const int n1 = __shfl(cc, j + 1, 32);
            const int n2 = __shfl(cc, j + 2, 32);
            const int n3 = __shfl(cc, j + 3, 32);
            const uint2 v0 = *(const uint2*)(xb + (size_t)n0 * 128 + 4 * l);
            const uint2 v1 = *(const uint2*)(xb + (size_t)n1 * 128 + 4 * l);
            const uint2 v2 = *(const uint2*)(xb + (size_t)n2 * 128 + 4 * l);
            const uint2 v3 = *(const uint2*)(xb + (size_t)n3 * 128 + 4 * l);
            ACC4(a0, v0); ACC4(a1, v1); ACC4(a0, v2); ACC4(a1, v3);
        }
        for (; j < cnt; ++j) {
            const int nn = __shfl(cc, j, 32);
            const uint2 v = *(const uint2*)(xb + (size_t)nn * 128 + 4 * l);
            ACC4(a0, v);
        }
    }
    const float inv = invd[node];
    uint2 o;
    o.x = pack2((a0.x + a1.x) * inv, (a0.y + a1.y) * inv);
    o.y = pack2((a0.z + a1.z) * inv, (a0.w + a1.w) * inv);
    *(uint2*)(aggb + (size_t)node * 128 + 4 * l) = o;
}

// ================= fused SAGE linear (d_out=128), bf16 in/out, relu ==========
__global__ __launch_bounds__(256) void k_mm128b(const u16* __restrict__ aggb,
                                                const u16* __restrict__ xrb,
                                                const float* __restrict__ Wl,
                                                const float* __restrict__ bl,
                                                const float* __restrict__ Wr,
                                                u16* __restrict__ outb, int n) {
    __shared__ float s_agg[64][128];
    __shared__ float s_x[64][128];
    const int row0 = blockIdx.x * 64;

    for (int idx = threadIdx.x; idx < 64 * 16; idx += 256) {
        const int r = idx >> 4, c = idx & 15;
        const int row = row0 + r;
        uint4 av = {0u, 0u, 0u, 0u}, xv = {0u, 0u, 0u, 0u};
        if (row < n) {
            av = *(const uint4*)(aggb + (size_t)row * 128 + c * 8);
            xv = *(const uint4*)(xrb  + (size_t)row * 128 + c * 8);
        }
        float* sa = &s_agg[r][c * 8];
        sa[0] = bflo(av.x); sa[1] = bfhi(av.x); sa[2] = bflo(av.y); sa[3] = bfhi(av.y);
        sa[4] = bflo(av.z); sa[5] = bfhi(av.z); sa[6] = bflo(av.w); sa[7] = bfhi(av.w);
        float* sx = &s_x[r][c * 8];
        sx[0] = bflo(xv.x); sx[1] = bfhi(xv.x); sx[2] = bflo(xv.y); sx[3] = bfhi(xv.y);
        sx[4] = bflo(xv.z); sx[5] = bfhi(xv.z); sx[6] = bflo(xv.w); sx[7] = bfhi(xv.w);
    }
    __syncthreads();

    const int lane32 = threadIdx.x & 31;
    const int rg = threadIdx.x >> 5;
    const float4* Wl4 = (const float4*)Wl;
    const float4* Wr4 = (const float4*)Wr;

    float4 acc[8];
#pragma unroll
    for (int j = 0; j < 8; ++j) acc[j] = make_float4(0.f, 0.f, 0.f, 0.f);

#pragma unroll 4
    for (int k = 0; k < 128; ++k) {
        const float4 wl = Wl4[k * 32 + lane32];
        const float4 wr = Wr4[k * 32 + lane32];
#pragma unroll
        for (int j = 0; j < 8; ++j) {
            const float a = s_agg[rg * 8 + j][k];
            const float xv = s_x[rg * 8 + j][k];
            acc[j].x = fmaf(a, wl.x, fmaf(xv, wr.x, acc[j].x));
            acc[j].y = fmaf(a, wl.y, fmaf(xv, wr.y, acc[j].y));
            acc[j].z = fmaf(a, wl.z, fmaf(xv, wr.z, acc[j].z));
            acc[j].w = fmaf(a, wl.w, fmaf(xv, wr.w, acc[j].w));
        }
    }

    const float4 bb = ((const float4*)bl)[lane32];
#pragma unroll
    for (int j = 0; j < 8; ++j) {
        const int row = row0 + rg * 8 + j;
        if (row >= n) break;
        float ox = fmaxf(acc[j].x + bb.x, 0.f);
        float oy = fmaxf(acc[j].y + bb.y, 0.f);
        float oz = fmaxf(acc[j].z + bb.z, 0.f);
        float ow = fmaxf(acc[j].w + bb.w, 0.f);
        uint2 o;
        o.x = pack2(ox, oy);
        o.y = pack2(oz, ow);
        *(uint2*)(outb + (size_t)row * 128 + 4 * lane32) = o;
    }
}

// ================= layer 3: t = h2@Wl3 (bf16 out), r = h2@Wr3 + bl3 (fp32) ===
__global__ __launch_bounds__(320) void k_dual40(const u16* __restrict__ hb,
                                                const float* __restrict__ Wl,
                                                const float* __restrict__ Wr,
                                                const float* __restrict__ bl,
                                                u16* __restrict__ t40b,
                                                float* __restrict__ r40, int n) {
    __shared__ float s_x[64][136];
    const int row0 = blockIdx.x * 64;

    for (int idx = threadIdx.x; idx < 64 * 16; idx += 320) {
        const int r = idx >> 4, c = idx & 15;
        const int row = row0 + r;
        uint4 xv = {0u, 0u, 0u, 0u};
        if (row < n) xv = *(const uint4*)(hb + (size_t)row * 128 + c * 8);
        float* sx = &s_x[r][c * 8];
        sx[0] = bflo(xv.x); sx[1] = bfhi(xv.x); sx[2] = bflo(xv.y); sx[3] = bfhi(xv.y);
        sx[4] = bflo(xv.z); sx[5] = bfhi(xv.z); sx[6] = bflo(xv.w); sx[7] = bfhi(xv.w);
    }
    __syncthreads();

    const int col = threadIdx.x % 40;
    const int g = threadIdx.x / 40;
    float at[8], ar[8];
#pragma unroll
    for (int j = 0; j < 8; ++j) { at[j] = 0.f; ar[j] = 0.f; }

#pragma unroll 4
    for (int k = 0; k < 128; ++k) {
        const float wl = Wl[k * 40 + col];
        const float wr = Wr[k * 40 + col];
#pragma unroll
        for (int j = 0; j < 8; ++j) {
            const float xv = s_x[g * 8 + j][k];
            at[j] = fmaf(xv, wl, at[j]);
            ar[j] = fmaf(xv, wr, ar[j]);
        }
    }

    const float b = bl[col];
#pragma unroll
    for (int j = 0; j < 8; ++j) {
        const int row = row0 + g * 8 + j;
        if (row >= n) break;
        t40b[(size_t)row * 40 + col] = (u16)f2bf1(at[j]);
        r40[(size_t)row * 40 + col] = ar[j] + b;
    }
}

// ================= layer 3 aggregation (d=40): out = invd*sum(t[nbr]) + r ====
__global__ __launch_bounds__(256) void k_agg40(const u16* __restrict__ t40b,
                                               const float* __restrict__ r40,
                                               const int* __restrict__ rowptr,
                                               const int* __restrict__ col,
                                               const float* __restrict__ invd,
                                               float* __restrict__ out, int n) {
    const int tt = blockIdx.x * 256 + threadIdx.x;
    const int node = tt >> 4;
    if (node >= n) return;
    const int l = tt & 15;
    const bool act = l < 10;
    const int s0 = rowptr[node], s1 = rowptr[node + 1];
    float4 a0 = {0.f, 0.f, 0.f, 0.f};
    float4 a1 = {0.f, 0.f, 0.f, 0.f};
    for (int cb = s0; cb < s1; cb += 16) {
        const int cnt = min(16, s1 - cb);
        const int cc = (cb + l < s1) ? col[cb + l] : 0;
        int j = 0;
        for (; j + 4 <= cnt; j += 4) {
            const int n0 = __shfl(cc, j, 16);
            const int n1 = __shfl(cc, j + 1, 16);
            const int n2 = __shfl(cc, j + 2, 16);
            const int n3 = __shfl(cc, j + 3, 16);
            if (act) {
                const uint2 v0 = *(const uint2*)(t40b + (size_t)n0 * 40 + 4 * l);
                const uint2 v1 = *(const uint2*)(t40b + (size_t)n1 * 40 + 4 * l);
                const uint2 v2 = *(const uint2*)(t40b + (size_t)n2 * 40 + 4 * l);
                const uint2 v3 = *(const uint2*)(t40b + (size_t)n3 * 40 + 4 * l);
                ACC4(a0, v0); ACC4(a1, v1); ACC4(a0, v2); ACC4(a1, v3);
            }
        }
        for (; j < cnt; ++j) {
            const int nn = __shfl(cc, j, 16);
            if (act) {
                const uint2 v = *(const uint2*)(t40b + (size_t)nn * 40 + 4 * l);
                ACC4(a0, v);
            }
        }
    }
    if (act) {
        const float inv = invd[node];
        const float4 rv = *(const float4*)(r40 + (size_t)node * 40 + 4 * l);
        float4 o;
        o.x = fmaf(a0.x + a1.x, inv, rv.x);
        o.y = fmaf(a0.y + a1.y, inv, rv.y);
        o.z = fmaf(a0.z + a1.z, inv, rv.z);
        o.w = fmaf(a0.w + a1.w, inv, rv.w);
        *(float4*)(out + (size_t)node * 40 + 4 * l) = o;
    }
}

extern "C" void kernel_launch(void* const* d_in, const int* in_sizes, int n_in,
                              void* d_out, int out_size, void* d_ws, size_t ws_size,
                              hipStream_t stream) {
    const float* x   = (const float*)d_in[0];
    const int*   ei  = (const int*)d_in[1];
    const float* Wl1 = (const float*)d_in[2];
    const float* bl1 = (const float*)d_in[3];
    const float* Wr1 = (const float*)d_in[4];
    const float* Wl2 = (const float*)d_in[5];
    const float* bl2 = (const float*)d_in[6];
    const float* Wr2 = (const float*)d_in[7];
    const float* Wl3 = (const float*)d_in[8];
    const float* bl3 = (const float*)d_in[9];
    const float* Wr3 = (const float*)d_in[10];
    float* out = (float*)d_out;

    const int N = in_sizes[0] / 128;
    const int E = in_sizes[1] / 2;
    const int* src = ei;
    const int* dst = ei + E;

    auto align1k = [](size_t v) { return (v + 1023) & ~(size_t)1023; };
    const size_t NB16 = (size_t)N * 128 * sizeof(u16);   // 25.6 MB

    char* ws = (char*)d_ws;
    size_t off = 0;
    int*   degi     = (int*)(ws + off);   off += align1k((size_t)N * 4);
    float* invd     = (float*)(ws + off); off += align1k((size_t)N * 4);
    int*   rowptr   = (int*)(ws + off);   off += align1k((size_t)(N + 1) * 4);
    int*   partials = (int*)(ws + off);   off += align1k(4096);
    int*   col      = (int*)(ws + off);   off += align1k((size_t)E * 4);
    u16*   aggb     = (u16*)(ws + off);   off += align1k(NB16);
    u16*   xb       = (u16*)(ws + off);   off += align1k(NB16);   // later: h2b
    char*  regionY  = (ws + off);         off += align1k(NB16);   // h1b, later t40b+r40
    u16*   h1b  = (u16*)regionY;
    u16*   h2b  = xb;                                     // xb dead after L1 mm
    u16*   t40b = (u16*)regionY;                          // h1b dead after L2 mm
    float* r40  = (float*)(regionY + align1k((size_t)N * 40 * sizeof(u16)));

    const int eBlocks    = idiv_up(E, 256);
    const int scanBlocks = idiv_up(N, 1024);
    const int castBlocks = idiv_up((long)N * 128, 2048);
    const int aggBlocks  = idiv_up((long)N * 32, 256);
    const int agg40Blk   = idiv_up((long)N * 16, 256);
    const int mmBlocks   = idiv_up(N, 64);
    const int rangeSize  = idiv_up(N, 8);

    // ---- cast x -> bf16 ----
    k_cast<<<castBlocks, 256, 0, stream>>>(x, (u32*)xb, (long)N * 128);

    // ---- CSR build ----
    hipMemsetAsync(degi, 0, (size_t)N * sizeof(int), stream);
    k_count<<<eBlocks, 256, 0, stream>>>(dst, degi, E);
    k_scan1<<<scanBlocks, 256, 0, stream>>>(degi, rowptr, invd, partials, N);
    k_scan2<<<1, 256, 0, stream>>>(partials, scanBlocks);
    k_scan3<<<scanBlocks, 256, 0, stream>>>(rowptr, partials, N, E);
    k_fillp<<<8 * FILL_BPG, 256, 0, stream>>>(src, dst, rowptr, degi, col, E, rangeSize);

    // ---- layer 1 ----
    k_aggb<<<aggBlocks, 256, 0, stream>>>(xb, rowptr, col, invd, aggb, N);
    k_mm128b<<<mmBlocks, 256, 0, stream>>>(aggb, xb, Wl1, bl1, Wr1, h1b, N);

    // ---- layer 2 ----
    k_aggb<<<aggBlocks, 256, 0, stream>>>(h1b, rowptr, col, invd, aggb, N);
    k_mm128b<<<mmBlocks, 256, 0, stream>>>(aggb, h1b, Wl2, bl2, Wr2, h2b, N);

    // ---- layer 3: transform-then-aggregate over d=40 ----
    k_dual40<<<mmBlocks, 320, 0, stream>>>(h2b, Wl3, Wr3, bl3, t40b, r40, N);
    k_agg40<<<agg40Blk, 256, 0, stream>>>(t40b, r40, rowptr, col, invd, out, N);
}

// Round 6
// 442.647 us; speedup vs baseline: 19.7027x; 1.2403x over previous
//
#include <hip/hip_runtime.h>

using u16 = unsigned short;
using u32 = unsigned int;
typedef __attribute__((ext_vector_type(8))) short short8;   // 8 bf16 (4 VGPRs)
typedef __attribute__((ext_vector_type(4))) float f32x4;    // MFMA acc

static inline int idiv_up(long a, long b) { return (int)((a + b - 1) / b); }

// ---------- bf16 helpers (packed pairs in u32, elem0 = low half) ----------
__device__ __forceinline__ float bflo(u32 p) { return __uint_as_float(p << 16); }
__device__ __forceinline__ float bfhi(u32 p) { return __uint_as_float(p & 0xffff0000u); }
__device__ __forceinline__ u32 f2bf1(float f) {
    u32 x = __float_as_uint(f);
    return (x + 0x7fffu + ((x >> 16) & 1u)) >> 16;   // RNE
}
__device__ __forceinline__ u32 pack2(float lo, float hi) {
    return f2bf1(lo) | (f2bf1(hi) << 16);
}

// ================= cast x (fp32) -> xb (bf16) =================
__global__ __launch_bounds__(256) void k_cast(const float* __restrict__ x,
                                              u32* __restrict__ xb, long nelem) {
    long i = ((long)blockIdx.x * 256 + threadIdx.x) * 8;
    if (i >= nelem) return;
    float4 v0 = *(const float4*)(x + i);
    float4 v1 = *(const float4*)(x + i + 4);
    uint4 o;
    o.x = pack2(v0.x, v0.y);
    o.y = pack2(v0.z, v0.w);
    o.z = pack2(v1.x, v1.y);
    o.w = pack2(v1.z, v1.w);
    *(uint4*)(xb + (i >> 1)) = o;
}

// ====== W prep: [Wl;Wr] (256x128 fp32) -> MFMA B-fragment-native bf16 ======
// tile = t*8+s (t = n-tile 0..7, s = k-step 0..7); per lane l, elems b=0..7:
//   k = s*32 + (l>>4)*8 + b, n = t*16 + (l&15)
// stored at wp[(tile*64 + l)*8 + b]  (one uint4 per (tile,lane))
__global__ __launch_bounds__(256) void k_wprep(const float* __restrict__ Wl,
                                               const float* __restrict__ Wr,
                                               u16* __restrict__ wp) {
    const int gid = blockIdx.x * 256 + threadIdx.x;
    if (gid >= 64 * 64) return;
    const int tile = gid >> 6, l = gid & 63;
    const int t = tile >> 3, s = tile & 7;
    const int n = t * 16 + (l & 15);
    const int k0 = s * 32 + (l >> 4) * 8;
    u32 w[4];
#pragma unroll
    for (int p = 0; p < 4; ++p) {
        const int ka = k0 + 2 * p, kb = ka + 1;
        const float va = (ka < 128) ? Wl[ka * 128 + n] : Wr[(ka - 128) * 128 + n];
        const float vb = (kb < 128) ? Wl[kb * 128 + n] : Wr[(kb - 128) * 128 + n];
        w[p] = pack2(va, vb);
    }
    uint4 o = {w[0], w[1], w[2], w[3]};
    *(uint4*)(wp + (size_t)gid * 8) = o;
}

// ================= CSR construction =================
__global__ __launch_bounds__(256) void k_count(const int* __restrict__ dst,
                                               int* __restrict__ degi, int E) {
    int e = blockIdx.x * 256 + threadIdx.x;
    if (e < E) atomicAdd(&degi[__builtin_nontemporal_load(&dst[e])], 1);
}

__global__ __launch_bounds__(256) void k_scan1(const int* __restrict__ degi,
                                               int* __restrict__ rowptr,
                                               float* __restrict__ invd,
                                               int* __restrict__ partials, int n) {
    __shared__ int wt[4];
    const int base = blockIdx.x * 1024 + threadIdx.x * 4;
    int v[4];
    int sum = 0;
#pragma unroll
    for (int j = 0; j < 4; ++j) {
        int g = base + j;
        v[j] = (g < n) ? degi[g] : 0;
        sum += v[j];
    }
    const int lane = threadIdx.x & 63;
    const int wid = threadIdx.x >> 6;
    int incl = sum;
    for (int off = 1; off < 64; off <<= 1) {
        int t = __shfl_up(incl, off, 64);
        if (lane >= off) incl += t;
    }
    if (lane == 63) wt[wid] = incl;
    __syncthreads();
    int woff = 0;
    for (int w = 0; w < wid; ++w) woff += wt[w];
    int run = woff + incl - sum;
#pragma unroll
    for (int j = 0; j < 4; ++j) {
        int g = base + j;
        if (g < n) {
            rowptr[g] = run;
            invd[g] = 1.0f / fmaxf((float)v[j], 1.0f);
        }
        run += v[j];
    }
    if (threadIdx.x == 255) partials[blockIdx.x] = woff + incl;
}

__global__ __launch_bounds__(256) void k_scan2(int* p, int nb) {
    __shared__ int wt[4];
    __shared__ int carry;
    if (threadIdx.x == 0) carry = 0;
    __syncthreads();
    for (int bs = 0; bs < nb; bs += 256) {
        const int i = bs + threadIdx.x;
        int v = (i < nb) ? p[i] : 0;
        const int lane = threadIdx.x & 63;
        const int wid = threadIdx.x >> 6;
        int incl = v;
        for (int off = 1; off < 64; off <<= 1) {
            int t = __shfl_up(incl, off, 64);
            if (lane >= off) incl += t;
        }
        if (lane == 63) wt[wid] = incl;
        __syncthreads();
        int woff = 0;
        for (int w = 0; w < wid; ++w) woff += wt[w];
        int excl = carry + woff + incl - v;
        if (i < nb) p[i] = excl;
        __syncthreads();
        if (threadIdx.x == 255) carry += woff + incl;
        __syncthreads();
    }
}

__global__ __launch_bounds__(256) void k_scan3(int* __restrict__ rowptr,
                                               const int* __restrict__ partials,
                                               int n, int E) {
    const int base = blockIdx.x * 1024;
    const int add = partials[blockIdx.x];
    for (int i = threadIdx.x; i < 1024; i += 256) {
        int g = base + i;
        if (g < n) rowptr[g] += add;
    }
    if (blockIdx.x == 0 && threadIdx.x == 0) rowptr[n] = E;
}

// Partitioned fill (8 dst-range groups -> per-XCD L2 retention of col region)
#define FILL_BPG 128
__global__ __launch_bounds__(256) void k_fillp(const int* __restrict__ src,
                                               const int* __restrict__ dst,
                                               const int* __restrict__ rowptr,
                                               int* __restrict__ degi,
                                               int* __restrict__ col,
                                               int E, int rangeSize) {
    const int g = blockIdx.x & 7;
    const int b = blockIdx.x >> 3;
    const int lo = g * rangeSize;
    const int hi = lo + rangeSize;
    const long chunk = (E + FILL_BPG - 1) / FILL_BPG;
    const long e0 = (long)b * chunk;
    const long e1 = (e0 + chunk < (long)E) ? e0 + chunk : (long)E;
    for (long e = e0 + threadIdx.x; e < e1; e += 256) {
        const int d = __builtin_nontemporal_load(&dst[e]);
        if (d >= lo && d < hi) {
            const int s = __builtin_nontemporal_load(&src[e]);
            const int old = atomicAdd(&degi[d], -1);
            col[rowptr[d] + old - 1] = s;
        }
    }
}

// ================= mean aggregation, d=128, bf16 in / bf16 out =================
#define ACC4(A, V)                                                     \
    A.x += bflo(V.x); A.y += bfhi(V.x); A.z += bflo(V.y); A.w += bfhi(V.y);

__global__ __launch_bounds__(256) void k_aggb(const u16* __restrict__ xb,
                                              const int* __restrict__ rowptr,
                                              const int* __restrict__ col,
                                              const float* __restrict__ invd,
                                              u16* __restrict__ aggb, int n) {
    const int t = blockIdx.x * 256 + threadIdx.x;
    const int node = t >> 5;
    if (node >= n) return;
    const int l = t & 31;
    const int s0 = rowptr[node], s1 = rowptr[node + 1];
    float4 a0 = {0.f, 0.f, 0.f, 0.f};
    float4 a1 = {0.f, 0.f, 0.f, 0.f};
    for (int cb = s0; cb < s1; cb += 32) {
        const int cnt = min(32, s1 - cb);
        const int cc = (cb + l < s1) ? col[cb + l] : 0;
        int j = 0;
        for (; j + 8 <= cnt; j += 8) {
            const int n0 = __shfl(cc, j, 32);
            const int n1 = __shfl(cc, j + 1, 32);
            const int n2 = __shfl(cc, j + 2, 32);
            const int n3 = __shfl(cc, j + 3, 32);
            const int n4 = __shfl(cc, j + 4, 32);
            const int n5 = __shfl(cc, j + 5, 32);
            const int n6 = __shfl(cc, j + 6, 32);
            const int n7 = __shfl(cc, j + 7, 32);
            const uint2 v0 = *(const uint2*)(xb + (size_t)n0 * 128 + 4 * l);
            const uint2 v1 = *(const uint2*)(xb + (size_t)n1 * 128 + 4 * l);
            const uint2 v2 = *(const uint2*)(xb + (size_t)n2 * 128 + 4 * l);
            const uint2 v3 = *(const uint2*)(xb + (size_t)n3 * 128 + 4 * l);
            const uint2 v4 = *(const uint2*)(xb + (size_t)n4 * 128 + 4 * l);
            const uint2 v5 = *(const uint2*)(xb + (size_t)n5 * 128 + 4 * l);
            const uint2 v6 = *(const uint2*)(xb + (size_t)n6 * 128 + 4 * l);
            const uint2 v7 = *(const uint2*)(xb + (size_t)n7 * 128 + 4 * l);
            ACC4(a0, v0); ACC4(a1, v1); ACC4(a0, v2); ACC4(a1, v3);
            ACC4(a0, v4); ACC4(a1, v5); ACC4(a0, v6); ACC4(a1, v7);
        }
        for (; j + 4 <= cnt; j += 4) {
            const int n0 = __shfl(cc, j, 32);
            const int n1 = __shfl(cc, j + 1, 32);
            const int n2 = __shfl(cc, j + 2, 32);
            const int n3 = __shfl(cc, j + 3, 32);
            const uint2 v0 = *(const uint2*)(xb + (size_t)n0 * 128 + 4 * l);
            const uint2 v1 = *(const uint2*)(xb + (size_t)n1 * 128 + 4 * l);
            const uint2 v2 = *(const uint2*)(xb + (size_t)n2 * 128 + 4 * l);
            const uint2 v3 = *(const uint2*)(xb + (size_t)n3 * 128 + 4 * l);
            ACC4(a0, v0); ACC4(a1, v1); ACC4(a0, v2); ACC4(a1, v3);
        }
        for (; j < cnt; ++j) {
            const int nn = __shfl(cc, j, 32);
            const uint2 v = *(const uint2*)(xb + (size_t)nn * 128 + 4 * l);
            ACC4(a0, v);
        }
    }
    const float inv = invd[node];
    uint2 o;
    o.x = pack2((a0.x + a1.x) * inv, (a0.y + a1.y) * inv);
    o.y = pack2((a0.z + a1.z) * inv, (a0.w + a1.w) * inv);
    *(uint2*)(aggb + (size_t)node * 128 + 4 * l) = o;
}

// ====== fused SAGE linear via MFMA: out = relu([agg|x] @ [Wl;Wr] + bl) ======
// 64 rows/block, 4 waves; wave w: rows w*16..w*16+15 x all 128 cols.
// A staged in LDS [64][264] bf16 (+8 pad -> 2-way-free ds_read_b128).
// B frags from wp (fragment-native, uint4/lane, L2-resident).
__global__ __launch_bounds__(256, 4) void k_mmf(const u16* __restrict__ aggb,
                                                const u16* __restrict__ xrb,
                                                const u16* __restrict__ wp,
                                                const float* __restrict__ bl,
                                                u16* __restrict__ outb, int n) {
    __shared__ __align__(16) u16 s_a[64][264];
    const int row0 = blockIdx.x * 64;
    const int tid = threadIdx.x;

    // stage A = [agg | x] rows row0..row0+63 (256 bf16/row)
#pragma unroll
    for (int it = 0; it < 8; ++it) {
        const int idx = tid + it * 256;          // 0..2047
        const int r = idx >> 5, c8 = idx & 31;   // 32 x uint4 per row
        const int row = row0 + r;
        uint4 v = {0u, 0u, 0u, 0u};
        if (row < n) {
            v = (c8 < 16) ? *(const uint4*)(aggb + (size_t)row * 128 + c8 * 8)
                          : *(const uint4*)(xrb + (size_t)row * 128 + (c8 - 16) * 8);
        }
        *(uint4*)(&s_a[r][c8 * 8]) = v;
    }
    __syncthreads();

    const int l = tid & 63;
    const int w = tid >> 6;                 // wave 0..3
    const int rloc = w * 16 + (l & 15);     // A-frag row in LDS
    const int q = l >> 4;                   // quarter-wave 0..3

    short8 afr[8];
#pragma unroll
    for (int s = 0; s < 8; ++s)
        afr[s] = *(const short8*)(&s_a[rloc][s * 32 + q * 8]);

    f32x4 acc[8];
#pragma unroll
    for (int t = 0; t < 8; ++t) acc[t] = (f32x4){0.f, 0.f, 0.f, 0.f};

#pragma unroll
    for (int t = 0; t < 8; ++t) {
#pragma unroll
        for (int s = 0; s < 8; ++s) {
            const short8 b = *(const short8*)(wp + ((size_t)(t * 8 + s) * 64 + l) * 8);
            acc[t] = __builtin_amdgcn_mfma_f32_16x16x32_bf16(afr[s], b, acc[t], 0, 0, 0);
        }
    }

    // epilogue: D col = lane&15, row = q*4 + reg  (m89-verified mapping)
    const int rowb = row0 + w * 16 + q * 4;
#pragma unroll
    for (int t = 0; t < 8; ++t) {
        const float bias = bl[t * 16 + (l & 15)];
#pragma unroll
        for (int r = 0; r < 4; ++r) {
            const int row = rowb + r;
            if (row < n) {
                const float o = fmaxf(acc[t][r] + bias, 0.f);
                outb[(size_t)row * 128 + t * 16 + (l & 15)] = (u16)f2bf1(o);
            }
        }
    }
}

// ================= layer 3: t = h2@Wl3 (bf16 out), r = h2@Wr3 + bl3 (fp32) ===
__global__ __launch_bounds__(320) void k_dual40(const u16* __restrict__ hb,
                                                const float* __restrict__ Wl,
                                                const float* __restrict__ Wr,
                                                const float* __restrict__ bl,
                                                u16* __restrict__ t40b,
                                                float* __restrict__ r40, int n) {
    __shared__ float s_x[64][136];
    const int row0 = blockIdx.x * 64;

    for (int idx = threadIdx.x; idx < 64 * 16; idx += 320) {
        const int r = idx >> 4, c = idx & 15;
        const int row = row0 + r;
        uint4 xv = {0u, 0u, 0u, 0u};
        if (row < n) xv = *(const uint4*)(hb + (size_t)row * 128 + c * 8);
        float* sx = &s_x[r][c * 8];
        sx[0] = bflo(xv.x); sx[1] = bfhi(xv.x); sx[2] = bflo(xv.y); sx[3] = bfhi(xv.y);
        sx[4] = bflo(xv.z); sx[5] = bfhi(xv.z); sx[6] = bflo(xv.w); sx[7] = bfhi(xv.w);
    }
    __syncthreads();

    const int col = threadIdx.x % 40;
    const int g = threadIdx.x / 40;
    float at[8], ar[8];
#pragma unroll
    for (int j = 0; j < 8; ++j) { at[j] = 0.f; ar[j] = 0.f; }

#pragma unroll 4
    for (int k = 0; k < 128; ++k) {
        const float wl = Wl[k * 40 + col];
        const float wr = Wr[k * 40 + col];
#pragma unroll
        for (int j = 0; j < 8; ++j) {
            const float xv = s_x[g * 8 + j][k];
            at[j] = fmaf(xv, wl, at[j]);
            ar[j] = fmaf(xv, wr, ar[j]);
        }
    }

    const float b = bl[col];
#pragma unroll
    for (int j = 0; j < 8; ++j) {
        const int row = row0 + g * 8 + j;
        if (row >= n) break;
        t40b[(size_t)row * 40 + col] = (u16)f2bf1(at[j]);
        r40[(size_t)row * 40 + col] = ar[j] + b;
    }
}

// ================= layer 3 aggregation (d=40): out = invd*sum(t[nbr]) + r ====
__global__ __launch_bounds__(256) void k_agg40(const u16* __restrict__ t40b,
                                               const float* __restrict__ r40,
                                               const int* __restrict__ rowptr,
                                               const int* __restrict__ col,
                                               const float* __restrict__ invd,
                                               float* __restrict__ out, int n) {
    const int tt = blockIdx.x * 256 + threadIdx.x;
    const int node = tt >> 4;
    if (node >= n) return;
    const int l = tt & 15;
    const bool act = l < 10;
    const int s0 = rowptr[node], s1 = rowptr[node + 1];
    float4 a0 = {0.f, 0.f, 0.f, 0.f};
    float4 a1 = {0.f, 0.f, 0.f, 0.f};
    for (int cb = s0; cb < s1; cb += 16) {
        const int cnt = min(16, s1 - cb);
        const int cc = (cb + l < s1) ? col[cb + l] : 0;
        int j = 0;
        for (; j + 4 <= cnt; j += 4) {
            const int n0 = __shfl(cc, j, 16);
            const int n1 = __shfl(cc, j + 1, 16);
            const int n2 = __shfl(cc, j + 2, 16);
            const int n3 = __shfl(cc, j + 3, 16);
            if (act) {
                const uint2 v0 = *(const uint2*)(t40b + (size_t)n0 * 40 + 4 * l);
                const uint2 v1 = *(const uint2*)(t40b + (size_t)n1 * 40 + 4 * l);
                const uint2 v2 = *(const uint2*)(t40b + (size_t)n2 * 40 + 4 * l);
                const uint2 v3 = *(const uint2*)(t40b + (size_t)n3 * 40 + 4 * l);
                ACC4(a0, v0); ACC4(a1, v1); ACC4(a0, v2); ACC4(a1, v3);
            }
        }
        for (; j < cnt; ++j) {
            const int nn = __shfl(cc, j, 16);
            if (act) {
                const uint2 v = *(const uint2*)(t40b + (size_t)nn * 40 + 4 * l);
                ACC4(a0, v);
            }
        }
    }
    if (act) {
        const float inv = invd[node];
        const float4 rv = *(const float4*)(r40 + (size_t)node * 40 + 4 * l);
        float4 o;
        o.x = fmaf(a0.x + a1.x, inv, rv.x);
        o.y = fmaf(a0.y + a1.y, inv, rv.y);
        o.z = fmaf(a0.z + a1.z, inv, rv.z);
        o.w = fmaf(a0.w + a1.w, inv, rv.w);
        *(float4*)(out + (size_t)node * 40 + 4 * l) = o;
    }
}

extern "C" void kernel_launch(void* const* d_in, const int* in_sizes, int n_in,
                              void* d_out, int out_size, void* d_ws, size_t ws_size,
                              hipStream_t stream) {
    const float* x   = (const float*)d_in[0];
    const int*   ei  = (const int*)d_in[1];
    const float* Wl1 = (const float*)d_in[2];
    const float* bl1 = (const float*)d_in[3];
    const float* Wr1 = (const float*)d_in[4];
    const float* Wl2 = (const float*)d_in[5];
    const float* bl2 = (const float*)d_in[6];
    const float* Wr2 = (const float*)d_in[7];
    const float* Wl3 = (const float*)d_in[8];
    const float* bl3 = (const float*)d_in[9];
    const float* Wr3 = (const float*)d_in[10];
    float* out = (float*)d_out;

    const int N = in_sizes[0] / 128;
    const int E = in_sizes[1] / 2;
    const int* src = ei;
    const int* dst = ei + E;

    auto align1k = [](size_t v) { return (v + 1023) & ~(size_t)1023; };
    const size_t NB16 = (size_t)N * 128 * sizeof(u16);   // 25.6 MB

    char* ws = (char*)d_ws;
    size_t off = 0;
    int*   degi     = (int*)(ws + off);   off += align1k((size_t)N * 4);
    float* invd     = (float*)(ws + off); off += align1k((size_t)N * 4);
    int*   rowptr   = (int*)(ws + off);   off += align1k((size_t)(N + 1) * 4);
    int*   partials = (int*)(ws + off);   off += align1k(4096);
    u16*   wp1      = (u16*)(ws + off);   off += align1k(64 * 1024);
    u16*   wp2      = (u16*)(ws + off);   off += align1k(64 * 1024);
    int*   col      = (int*)(ws + off);   off += align1k((size_t)E * 4);
    u16*   aggb     = (u16*)(ws + off);   off += align1k(NB16);
    u16*   xb       = (u16*)(ws + off);   off += align1k(NB16);   // later: h2b
    char*  regionY  = (ws + off);         off += align1k(NB16);   // h1b, later t40b+r40
    u16*   h1b  = (u16*)regionY;
    u16*   h2b  = xb;                                     // xb dead after L1 mm
    u16*   t40b = (u16*)regionY;                          // h1b dead after L2 mm
    float* r40  = (float*)(regionY + align1k((size_t)N * 40 * sizeof(u16)));

    const int eBlocks    = idiv_up(E, 256);
    const int scanBlocks = idiv_up(N, 1024);
    const int castBlocks = idiv_up((long)N * 128, 2048);
    const int aggBlocks  = idiv_up((long)N * 32, 256);
    const int agg40Blk   = idiv_up((long)N * 16, 256);
    const int mmBlocks   = idiv_up(N, 64);
    const int rangeSize  = idiv_up(N, 8);

    // ---- cast x -> bf16 ; W preps ----
    k_cast<<<castBlocks, 256, 0, stream>>>(x, (u32*)xb, (long)N * 128);
    k_wprep<<<16, 256, 0, stream>>>(Wl1, Wr1, wp1);
    k_wprep<<<16, 256, 0, stream>>>(Wl2, Wr2, wp2);

    // ---- CSR build ----
    hipMemsetAsync(degi, 0, (size_t)N * sizeof(int), stream);
    k_count<<<eBlocks, 256, 0, stream>>>(dst, degi, E);
    k_scan1<<<scanBlocks, 256, 0, stream>>>(degi, rowptr, invd, partials, N);
    k_scan2<<<1, 256, 0, stream>>>(partials, scanBlocks);
    k_scan3<<<scanBlocks, 256, 0, stream>>>(rowptr, partials, N, E);
    k_fillp<<<8 * FILL_BPG, 256, 0, stream>>>(src, dst, rowptr, degi, col, E, rangeSize);

    // ---- layer 1 ----
    k_aggb<<<aggBlocks, 256, 0, stream>>>(xb, rowptr, col, invd, aggb, N);
    k_mmf<<<mmBlocks, 256, 0, stream>>>(aggb, xb, wp1, bl1, h1b, N);

    // ---- layer 2 ----
    k_aggb<<<aggBlocks, 256, 0, stream>>>(h1b, rowptr, col, invd, aggb, N);
    k_mmf<<<mmBlocks, 256, 0, stream>>>(aggb, h1b, wp2, bl2, h2b, N);

    // ---- layer 3: transform-then-aggregate over d=40 ----
    k_dual40<<<mmBlocks, 320, 0, stream>>>(h2b, Wl3, Wr3, bl3, t40b, r40, N);
    k_agg40<<<agg40Blk, 256, 0, stream>>>(t40b, r40, rowptr, col, invd, out, N);
}